// Round 3
// baseline (2713.545 us; speedup 1.0000x reference)
//
#include <hip/hip_runtime.h>
#include <hip/hip_bf16.h>

// Transformer block: LN1 -> QKV -> MHA(16 heads, hd=64) -> out-proj + resid
//                    -> LN2 -> FFN(4x, ReLU) + resid
// B=2, S=2048, D=1024, H=16, hd=64, F=4096. M = B*S = 4096 rows.
//
// Round 3: dtype fix. Buffers are FP32 (per reference contract; rounds 1-2
// read them as bf16 -> ~0.4% NaN bit patterns -> absmax NaN). Inputs/output
// fp32; intermediates bf16 (fp32 accumulation). Flash-style attention
// (TQ=64 q-rows/block) replaces the per-row kernel. FFN chunked 4x so peak
// workspace = 32 MB.
//
// Workspace (all bf16, peak 32 MB):
//   xn   [0, 8MB)   LN1 out             (dead after v-proj)
//   qb   [8,16MB)   Q                   (dead after attn)
//   kb   [16,24MB)  K                   (dead after attn)
//   vb   [24,32MB)  V                   (dead after attn)
//   att  = xn       attention out       (dead after out-proj)
//   x2   = qb       residual carrier    (live to end)
//   xn2  = kb       LN2 out             (dead after FFN-up)
//   hidc = vb       FFN hidden chunk [1024,4096]

using bf16 = __hip_bfloat16;

__device__ __forceinline__ float toF(float v) { return v; }
__device__ __forceinline__ float toF(bf16 v) { return __bfloat162float(v); }
__device__ __forceinline__ void storeF(float* p, float v) { *p = v; }
__device__ __forceinline__ void storeF(bf16* p, float v) { *p = __float2bfloat16(v); }

// raw ushort -> float (bf16 decode)
__device__ __forceinline__ float bfu(unsigned short u) {
    union { float f; unsigned int i; } c;
    c.i = ((unsigned int)u) << 16;
    return c.f;
}

__device__ __forceinline__ float waveReduceSum(float v) {
    #pragma unroll
    for (int o = 32; o > 0; o >>= 1) v += __shfl_down(v, o, 64);
    return v;
}

__device__ __forceinline__ float4 load4bf(const bf16* p) {
    const __hip_bfloat162* p2 = (const __hip_bfloat162*)p;
    float2 a = __bfloat1622float2(p2[0]);
    float2 b = __bfloat1622float2(p2[1]);
    return make_float4(a.x, a.y, b.x, b.y);
}

// ---------------- LayerNorm: InT x -> bf16 out ----------------
template <typename InT>
__global__ __launch_bounds__(256) void ln_kernel(const InT* __restrict__ x,
                                                 const float* __restrict__ g,
                                                 const float* __restrict__ b,
                                                 bf16* __restrict__ out, int D) {
    const int row = blockIdx.x;
    const InT* xr = x + (size_t)row * D;
    float s = 0.f, s2 = 0.f;
    for (int i = threadIdx.x; i < D; i += 256) {
        float v = toF(xr[i]);
        s += v; s2 += v * v;
    }
    __shared__ float ws[4], ws2[4];
    int lane = threadIdx.x & 63, wid = threadIdx.x >> 6;
    s = waveReduceSum(s); s2 = waveReduceSum(s2);
    if (lane == 0) { ws[wid] = s; ws2[wid] = s2; }
    __syncthreads();
    float ts = ws[0] + ws[1] + ws[2] + ws[3];
    float ts2 = ws2[0] + ws2[1] + ws2[2] + ws2[3];
    float mean = ts / D;
    float var = ts2 / D - mean * mean;
    float rstd = rsqrtf(var + 1e-5f);
    bf16* outr = out + (size_t)row * D;
    for (int i = threadIdx.x; i < D; i += 256) {
        float v = (toF(xr[i]) - mean) * rstd * g[i] + b[i];
        outr[i] = __float2bfloat16(v);
    }
}

// ---------------- GEMM: C = act(A@W + bias) [+ resid] ----------------
// A [M,K] bf16, W [K,N] fp32, bias fp32, C [M,N] OutT, resid ResidT
template <typename OutT, typename ResidT, bool RELU, bool HAS_RESID>
__global__ __launch_bounds__(256) void gemm_kernel(const bf16* __restrict__ A,
                                                   const float* __restrict__ W,
                                                   const float* __restrict__ bias,
                                                   const ResidT* __restrict__ resid,
                                                   OutT* __restrict__ C,
                                                   int M, int N, int K) {
    const int n0 = blockIdx.x * 64;
    const int m0 = blockIdx.y * 64;
    const int tid = threadIdx.x;
    const int tx = tid & 15, ty = tid >> 4;  // 16x16 threads, 4x4 microtile

    __shared__ float As[16][64];   // [k][m]
    __shared__ float Ws[16][64];   // [k][n]

    float acc[4][4];
    #pragma unroll
    for (int i = 0; i < 4; ++i)
        #pragma unroll
        for (int j = 0; j < 4; ++j) acc[i][j] = 0.f;

    const int ar = tid >> 2;            // 0..63 row within A-tile
    const int akc = (tid & 3) * 4;      // k sub-offset
    const int wk = tid >> 4;            // 0..15 k within W-tile
    const int wc = (tid & 15) * 4;      // col sub-offset

    for (int k0 = 0; k0 < K; k0 += 16) {
        float4 a4 = load4bf(A + (size_t)(m0 + ar) * K + k0 + akc);
        float4 w4 = *(const float4*)(W + (size_t)(k0 + wk) * N + n0 + wc);
        As[akc + 0][ar] = a4.x;
        As[akc + 1][ar] = a4.y;
        As[akc + 2][ar] = a4.z;
        As[akc + 3][ar] = a4.w;
        Ws[wk][wc + 0] = w4.x;
        Ws[wk][wc + 1] = w4.y;
        Ws[wk][wc + 2] = w4.z;
        Ws[wk][wc + 3] = w4.w;
        __syncthreads();
        #pragma unroll
        for (int kk = 0; kk < 16; ++kk) {
            float a[4], b[4];
            #pragma unroll
            for (int i = 0; i < 4; ++i) a[i] = As[kk][ty * 4 + i];
            #pragma unroll
            for (int j = 0; j < 4; ++j) b[j] = Ws[kk][tx * 4 + j];
            #pragma unroll
            for (int i = 0; i < 4; ++i)
                #pragma unroll
                for (int j = 0; j < 4; ++j) acc[i][j] += a[i] * b[j];
        }
        __syncthreads();
    }

    #pragma unroll
    for (int i = 0; i < 4; ++i) {
        int row = m0 + ty * 4 + i;
        #pragma unroll
        for (int j = 0; j < 4; ++j) {
            int col = n0 + tx * 4 + j;
            float v = acc[i][j] + bias[col];
            if (RELU) v = fmaxf(v, 0.f);
            if (HAS_RESID) v += toF(resid[(size_t)row * N + col]);
            storeF(&C[(size_t)row * N + col], v);
        }
    }
}

// ---------------- Flash attention (scalar, TQ=64 q-rows / block) ----------
// grid (S/64, H, B), block 256 (4 waves). Wave w handles tile rows
// [w*16,(w+1)*16); lane = q-row. K/V tiles staged to LDS as fp32.
__global__ __launch_bounds__(256) void attn_flash(const bf16* __restrict__ q,
                                                  const bf16* __restrict__ k,
                                                  const bf16* __restrict__ v,
                                                  const int* __restrict__ mask,
                                                  bf16* __restrict__ out,
                                                  int B, int S, int H, int hd) {
    const int q0 = blockIdx.x * 64;
    const int h = blockIdx.y, b = blockIdx.z;
    const int D = H * hd;  // 1024
    const int tid = threadIdx.x;
    const int lane = tid & 63, wid = tid >> 6;

    __shared__ float Ks[64][64];
    __shared__ float Vs[64][64];
    __shared__ int   Msk[64];
    __shared__ float mred[4][64], lred[4][64], linv[64];
    __shared__ float Oacc[64][65];

    // q row (lane) into registers, pre-scaled by 1/sqrt(64)
    float qr[64];
    const bf16* qp = q + ((size_t)(b * S + q0 + lane)) * D + h * hd;
    #pragma unroll
    for (int i = 0; i < 64; i += 4) {
        ushort4 u = *(const ushort4*)(qp + i);
        qr[i + 0] = bfu(u.x) * 0.125f;
        qr[i + 1] = bfu(u.y) * 0.125f;
        qr[i + 2] = bfu(u.z) * 0.125f;
        qr[i + 3] = bfu(u.w) * 0.125f;
    }

    float Ov[64];
    #pragma unroll
    for (int i = 0; i < 64; ++i) Ov[i] = 0.f;
    float m = -1e30f, l = 0.f;

    const int r = tid >> 2;          // tile row this thread stages
    const int dq = (tid & 3) * 16;   // col start

    for (int j0 = 0; j0 < S; j0 += 64) {
        const bf16* kp = k + ((size_t)(b * S + j0 + r)) * D + h * hd + dq;
        const bf16* vp = v + ((size_t)(b * S + j0 + r)) * D + h * hd + dq;
        #pragma unroll
        for (int i = 0; i < 16; i += 4) {
            ushort4 u = *(const ushort4*)(kp + i);
            *(float4*)&Ks[r][dq + i] = make_float4(bfu(u.x), bfu(u.y), bfu(u.z), bfu(u.w));
        }
        #pragma unroll
        for (int i = 0; i < 16; i += 4) {
            ushort4 u = *(const ushort4*)(vp + i);
            *(float4*)&Vs[r][dq + i] = make_float4(bfu(u.x), bfu(u.y), bfu(u.z), bfu(u.w));
        }
        if (tid < 64) Msk[tid] = mask[b * S + j0 + tid];
        __syncthreads();

        // scores for this wave's 16 tile-rows (LDS reads are wave-uniform
        // -> broadcast, conflict-free)
        float s[16];
        float mt = m;
        #pragma unroll
        for (int jj = 0; jj < 16; ++jj) {
            int j = wid * 16 + jj;
            float acc = 0.f;
            #pragma unroll
            for (int d4 = 0; d4 < 16; ++d4) {
                float4 kk = *(const float4*)&Ks[j][d4 * 4];
                acc += qr[d4 * 4 + 0] * kk.x + qr[d4 * 4 + 1] * kk.y
                     + qr[d4 * 4 + 2] * kk.z + qr[d4 * 4 + 3] * kk.w;
            }
            if (Msk[j] == 0) acc = -1e9f;
            s[jj] = acc;
            mt = fmaxf(mt, acc);
        }
        float f = __expf(m - mt);
        l *= f;
        #pragma unroll
        for (int i = 0; i < 64; ++i) Ov[i] *= f;
        m = mt;
        #pragma unroll
        for (int jj = 0; jj < 16; ++jj) {
            int j = wid * 16 + jj;
            float p = __expf(s[jj] - m);
            l += p;
            #pragma unroll
            for (int d4 = 0; d4 < 16; ++d4) {
                float4 vv = *(const float4*)&Vs[j][d4 * 4];
                Ov[d4 * 4 + 0] += p * vv.x;
                Ov[d4 * 4 + 1] += p * vv.y;
                Ov[d4 * 4 + 2] += p * vv.z;
                Ov[d4 * 4 + 3] += p * vv.w;
            }
        }
        __syncthreads();  // before next tile overwrites Ks/Vs
    }

    // merge the 4 per-wave partials (each wave saw a disjoint j-subset)
    mred[wid][lane] = m;
    lred[wid][lane] = l;
    for (int i = tid; i < 64 * 65; i += 256) ((float*)Oacc)[i] = 0.f;
    __syncthreads();
    float gm = fmaxf(fmaxf(mred[0][lane], mred[1][lane]),
                     fmaxf(mred[2][lane], mred[3][lane]));
    float scale = __expf(m - gm);
    float lsum = lred[0][lane] * __expf(mred[0][lane] - gm)
               + lred[1][lane] * __expf(mred[1][lane] - gm)
               + lred[2][lane] * __expf(mred[2][lane] - gm)
               + lred[3][lane] * __expf(mred[3][lane] - gm);
    if (wid == 0) linv[lane] = (lsum > 0.f) ? (1.f / lsum) : 0.f;
    for (int w = 0; w < 4; ++w) {
        if (wid == w) {
            #pragma unroll
            for (int i = 0; i < 64; ++i) Oacc[lane][i] += scale * Ov[i];
        }
        __syncthreads();
    }

    // write out: thread -> (qi = tid>>2, 16 dims)
    {
        const int qi = tid >> 2, d0 = (tid & 3) * 16;
        float inv = linv[qi];
        bf16* op = out + ((size_t)(b * S + q0 + qi)) * D + h * hd + d0;
        #pragma unroll
        for (int i = 0; i < 16; ++i) op[i] = __float2bfloat16(Oacc[qi][d0 + i] * inv);
    }
}

extern "C" void kernel_launch(void* const* d_in, const int* in_sizes, int n_in,
                              void* d_out, int out_size, void* d_ws, size_t ws_size,
                              hipStream_t stream) {
    const int B = 2, S = 2048, D = 1024, H = 16, hd = 64, F = 4096;
    const int M = B * S;  // 4096

    const float* x   = (const float*)d_in[0];
    const int*   mask= (const int*)  d_in[1];
    const float* wq  = (const float*)d_in[2];
    const float* bq  = (const float*)d_in[3];
    const float* wk  = (const float*)d_in[4];
    const float* bk  = (const float*)d_in[5];
    const float* wv  = (const float*)d_in[6];
    const float* bv  = (const float*)d_in[7];
    const float* wo  = (const float*)d_in[8];
    const float* bo  = (const float*)d_in[9];
    const float* g1  = (const float*)d_in[10];
    const float* be1 = (const float*)d_in[11];
    const float* g2  = (const float*)d_in[12];
    const float* be2 = (const float*)d_in[13];
    const float* w1  = (const float*)d_in[14];
    const float* bf1 = (const float*)d_in[15];
    const float* w2  = (const float*)d_in[16];
    const float* bf2 = (const float*)d_in[17];
    float* out = (float*)d_out;

    // Workspace (bf16 intermediates), peak 32 MB — see header comment.
    char* ws = (char*)d_ws;
    const size_t MB = 1024 * 1024;
    bf16* xn   = (bf16*)(ws + 0 * MB);
    bf16* qb   = (bf16*)(ws + 8 * MB);
    bf16* kb   = (bf16*)(ws + 16 * MB);
    bf16* vb   = (bf16*)(ws + 24 * MB);
    bf16* att  = xn;    // reuse (xn dead after QKV)
    bf16* x2   = qb;    // reuse (qb dead after attn)
    bf16* xn2  = kb;    // reuse (kb dead after attn)
    bf16* hidc = vb;    // reuse (vb dead after attn), [1024,4096] chunk

    // LN1: x(fp32) -> xn(bf16)
    ln_kernel<float><<<M, 256, 0, stream>>>(x, g1, be1, xn, D);

    // QKV projections
    dim3 gDD(D / 64, M / 64);
    gemm_kernel<bf16, float, false, false><<<gDD, 256, 0, stream>>>(xn, wq, bq, (const float*)nullptr, qb, M, D, D);
    gemm_kernel<bf16, float, false, false><<<gDD, 256, 0, stream>>>(xn, wk, bk, (const float*)nullptr, kb, M, D, D);
    gemm_kernel<bf16, float, false, false><<<gDD, 256, 0, stream>>>(xn, wv, bv, (const float*)nullptr, vb, M, D, D);

    // flash attention: q,k,v -> att
    attn_flash<<<dim3(S / 64, H, B), 256, 0, stream>>>(qb, kb, vb, mask, att, B, S, H, hd);

    // out-proj + residual(x, fp32) -> x2 (bf16)
    gemm_kernel<bf16, float, false, true><<<gDD, 256, 0, stream>>>(att, wo, bo, x, x2, M, D, D);

    // LN2: x2(bf16) -> xn2(bf16)
    ln_kernel<bf16><<<M, 256, 0, stream>>>(x2, g2, be2, xn2, D);

    // FFN in 4 row-chunks of 1024 (peak ws stays 32 MB)
    const int CH = 1024;
    for (int c = 0; c < M / CH; ++c) {
        const size_t roff = (size_t)c * CH;
        // up + ReLU: xn2[chunk] @ w1 -> hidc (bf16)
        gemm_kernel<bf16, float, true, false><<<dim3(F / 64, CH / 64), 256, 0, stream>>>(
            xn2 + roff * D, w1, bf1, (const float*)nullptr, hidc, CH, F, D);
        // down + residual(x2[chunk]) -> out[chunk] (fp32)
        gemm_kernel<float, bf16, false, true><<<dim3(D / 64, CH / 64), 256, 0, stream>>>(
            hidc, w2, bf2, x2 + roff * D, out + roff * D, CH, D, F);
    }
}

// Round 4
// 1211.559 us; speedup vs baseline: 2.2397x; 2.2397x over previous
//
#include <hip/hip_runtime.h>
#include <hip/hip_bf16.h>

// Transformer block: LN1 -> QKV -> MHA(16 heads, hd=64) -> out-proj + resid
//                    -> LN2 -> FFN(4x, ReLU) + resid
// B=2, S=2048, D=1024, H=16, hd=64, F=4096. M = B*S = 4096.
// fp32 buffers in/out; bf16 intermediates (fp32 accumulation).
//
// Round 4: dense GEMMs moved to bf16 MFMA (m97 structure: 128x128x32 tile,
// global_load_lds width=16 staging, 16 mfma_f32_16x16x32_bf16 + 8
// ds_read_b128 per wave per K-tile). Weights transposed+cast once per launch
// to bf16 [N,K] (B-fragment wants contiguous k). Attention unchanged from
// round 3 (891 us; MFMA flash attn is next round's change).
//
// Workspace:
//   [0,2)MB wqT, [2,4) wkT, [4,6) wvT, [6,8) woT   bf16 [1024,1024]
//   [8,16) w1T bf16 [4096,1024], [16,24) w2T bf16 [1024,4096]
//   [24,32) xn  -> att reuse
//   [32,40) qb  -> x2 reuse
//   [40,48) kb  -> xn2 reuse
//   [48,56) vb  -> FFN hid chunk reuse (extends to 80MB if ws_size allows)

using bf16 = __hip_bfloat16;
typedef short bf16x8 __attribute__((ext_vector_type(8)));
typedef float f32x4 __attribute__((ext_vector_type(4)));

__device__ __forceinline__ float toF(float v) { return v; }
__device__ __forceinline__ float toF(bf16 v) { return __bfloat162float(v); }
__device__ __forceinline__ void storeF(float* p, float v) { *p = v; }
__device__ __forceinline__ void storeF(bf16* p, float v) { *p = __float2bfloat16(v); }

__device__ __forceinline__ float bfu(unsigned short u) {
    union { float f; unsigned int i; } c;
    c.i = ((unsigned int)u) << 16;
    return c.f;
}

__device__ __forceinline__ float waveReduceSum(float v) {
    #pragma unroll
    for (int o = 32; o > 0; o >>= 1) v += __shfl_down(v, o, 64);
    return v;
}

// async global->LDS, 16B per lane; lptr must be wave-uniform, HW scatters
// lane l to lptr + l*16.
__device__ __forceinline__ void async16(const bf16* g, bf16* l) {
    __builtin_amdgcn_global_load_lds(
        (const __attribute__((address_space(1))) unsigned int*)g,
        (__attribute__((address_space(3))) unsigned int*)l,
        16, 0, 0);
}

// ---------------- weight transpose + cast: fp32 [R,C] -> bf16 [C,R] --------
__global__ __launch_bounds__(256) void transpose_cast(const float* __restrict__ in,
                                                      bf16* __restrict__ outT,
                                                      int R, int C) {
    __shared__ float t[32][33];
    const int c0 = blockIdx.x * 32, r0 = blockIdx.y * 32;
    const int lx = threadIdx.x & 31, ly = threadIdx.x >> 5;  // 32 x 8
    #pragma unroll
    for (int i = 0; i < 32; i += 8)
        t[ly + i][lx] = in[(size_t)(r0 + ly + i) * C + c0 + lx];
    __syncthreads();
    #pragma unroll
    for (int i = 0; i < 32; i += 8)
        outT[(size_t)(c0 + ly + i) * R + r0 + lx] = __float2bfloat16(t[lx][ly + i]);
}

// ---------------- LayerNorm: InT x -> bf16 out ----------------
template <typename InT>
__global__ __launch_bounds__(256) void ln_kernel(const InT* __restrict__ x,
                                                 const float* __restrict__ g,
                                                 const float* __restrict__ b,
                                                 bf16* __restrict__ out, int D) {
    const int row = blockIdx.x;
    const InT* xr = x + (size_t)row * D;
    float s = 0.f, s2 = 0.f;
    for (int i = threadIdx.x; i < D; i += 256) {
        float v = toF(xr[i]);
        s += v; s2 += v * v;
    }
    __shared__ float ws[4], ws2[4];
    int lane = threadIdx.x & 63, wid = threadIdx.x >> 6;
    s = waveReduceSum(s); s2 = waveReduceSum(s2);
    if (lane == 0) { ws[wid] = s; ws2[wid] = s2; }
    __syncthreads();
    float ts = ws[0] + ws[1] + ws[2] + ws[3];
    float ts2 = ws2[0] + ws2[1] + ws2[2] + ws2[3];
    float mean = ts / D;
    float var = ts2 / D - mean * mean;
    float rstd = rsqrtf(var + 1e-5f);
    bf16* outr = out + (size_t)row * D;
    for (int i = threadIdx.x; i < D; i += 256) {
        float v = (toF(xr[i]) - mean) * rstd * g[i] + b[i];
        outr[i] = __float2bfloat16(v);
    }
}

// ---------------- MFMA GEMM: C = act(A @ BT^T + bias) [+ resid] ------------
// A [M,K] bf16 row-major, BT [N,K] bf16 row-major (i.e. W transposed).
// 128x128x32 tile, 256 threads = 4 waves in 2x2; each wave 64x64 via 4x4
// mfma_f32_16x16x32_bf16. m97 structure (global_load_lds w16, 2-barrier).
template <typename OutT, typename ResidT, bool RELU, bool HAS_RESID>
__global__ __launch_bounds__(256) void gemm_mfma(const bf16* __restrict__ A,
                                                 const bf16* __restrict__ BT,
                                                 const float* __restrict__ bias,
                                                 const ResidT* __restrict__ resid,
                                                 OutT* __restrict__ C,
                                                 int M, int N, int K) {
    constexpr int BK = 32;
    __shared__ bf16 As[128][BK];  // 8 KB, row stride 64 B
    __shared__ bf16 Bs[128][BK];  // 8 KB
    const int tid = threadIdx.x, lane = tid & 63, wid = tid >> 6;
    const int m0 = blockIdx.y * 128, n0 = blockIdx.x * 128;
    const int wm = (wid >> 1) * 64, wn = (wid & 1) * 64;

    f32x4 acc[4][4] = {};

    // staging: wave w stages rows [w*16, w*16+16) and [64+w*16, ...)
    // lane l -> row offset (l>>2), 16B chunk (l&3) within the 64B row.
    const int srow = wid * 16 + (lane >> 2);
    const int scol = (lane & 3) * 8;           // bf16 elements
    const size_t aBase0 = (size_t)(m0 + srow) * K + scol;
    const size_t aBase1 = (size_t)(m0 + 64 + srow) * K + scol;
    const size_t bBase0 = (size_t)(n0 + srow) * K + scol;
    const size_t bBase1 = (size_t)(n0 + 64 + srow) * K + scol;

    const int fr = lane & 15;         // row (A) / col (B) within 16
    const int fk = (lane >> 4) * 8;   // k offset within 32

    for (int k0 = 0; k0 < K; k0 += BK) {
        async16(A + aBase0 + k0, &As[wid * 16][0]);
        async16(A + aBase1 + k0, &As[64 + wid * 16][0]);
        async16(BT + bBase0 + k0, &Bs[wid * 16][0]);
        async16(BT + bBase1 + k0, &Bs[64 + wid * 16][0]);
        __syncthreads();

        bf16x8 aF[4], bF[4];
        #pragma unroll
        for (int i = 0; i < 4; ++i)
            aF[i] = *(const bf16x8*)&As[wm + i * 16 + fr][fk];
        #pragma unroll
        for (int j = 0; j < 4; ++j)
            bF[j] = *(const bf16x8*)&Bs[wn + j * 16 + fr][fk];
        #pragma unroll
        for (int i = 0; i < 4; ++i)
            #pragma unroll
            for (int j = 0; j < 4; ++j)
                acc[i][j] = __builtin_amdgcn_mfma_f32_16x16x32_bf16(
                    aF[i], bF[j], acc[i][j], 0, 0, 0);
        __syncthreads();
    }

    // epilogue: C/D layout col=lane&15, row=(lane>>4)*4+r  [m89/m91 verified]
    const int col_l = lane & 15, row_l = (lane >> 4) * 4;
    #pragma unroll
    for (int j = 0; j < 4; ++j) {
        const int col = n0 + wn + j * 16 + col_l;
        const float bv = bias[col];
        #pragma unroll
        for (int i = 0; i < 4; ++i) {
            #pragma unroll
            for (int r = 0; r < 4; ++r) {
                const int row = m0 + wm + i * 16 + row_l + r;
                float v = acc[i][j][r] + bv;
                if (RELU) v = fmaxf(v, 0.f);
                if (HAS_RESID) v += toF(resid[(size_t)row * N + col]);
                storeF(&C[(size_t)row * N + col], v);
            }
        }
    }
}

// ---------------- Flash attention (round-3 kernel, unchanged) --------------
__global__ __launch_bounds__(256) void attn_flash(const bf16* __restrict__ q,
                                                  const bf16* __restrict__ k,
                                                  const bf16* __restrict__ v,
                                                  const int* __restrict__ mask,
                                                  bf16* __restrict__ out,
                                                  int B, int S, int H, int hd) {
    const int q0 = blockIdx.x * 64;
    const int h = blockIdx.y, b = blockIdx.z;
    const int D = H * hd;
    const int tid = threadIdx.x;
    const int lane = tid & 63, wid = tid >> 6;

    __shared__ float Ks[64][64];
    __shared__ float Vs[64][64];
    __shared__ int   Msk[64];
    __shared__ float mred[4][64], lred[4][64], linv[64];
    __shared__ float Oacc[64][65];

    float qr[64];
    const bf16* qp = q + ((size_t)(b * S + q0 + lane)) * D + h * hd;
    #pragma unroll
    for (int i = 0; i < 64; i += 4) {
        ushort4 u = *(const ushort4*)(qp + i);
        qr[i + 0] = bfu(u.x) * 0.125f;
        qr[i + 1] = bfu(u.y) * 0.125f;
        qr[i + 2] = bfu(u.z) * 0.125f;
        qr[i + 3] = bfu(u.w) * 0.125f;
    }

    float Ov[64];
    #pragma unroll
    for (int i = 0; i < 64; ++i) Ov[i] = 0.f;
    float m = -1e30f, l = 0.f;

    const int r = tid >> 2;
    const int dq = (tid & 3) * 16;

    for (int j0 = 0; j0 < S; j0 += 64) {
        const bf16* kp = k + ((size_t)(b * S + j0 + r)) * D + h * hd + dq;
        const bf16* vp = v + ((size_t)(b * S + j0 + r)) * D + h * hd + dq;
        #pragma unroll
        for (int i = 0; i < 16; i += 4) {
            ushort4 u = *(const ushort4*)(kp + i);
            *(float4*)&Ks[r][dq + i] = make_float4(bfu(u.x), bfu(u.y), bfu(u.z), bfu(u.w));
        }
        #pragma unroll
        for (int i = 0; i < 16; i += 4) {
            ushort4 u = *(const ushort4*)(vp + i);
            *(float4*)&Vs[r][dq + i] = make_float4(bfu(u.x), bfu(u.y), bfu(u.z), bfu(u.w));
        }
        if (tid < 64) Msk[tid] = mask[b * S + j0 + tid];
        __syncthreads();

        float s[16];
        float mt = m;
        #pragma unroll
        for (int jj = 0; jj < 16; ++jj) {
            int j = wid * 16 + jj;
            float acc = 0.f;
            #pragma unroll
            for (int d4 = 0; d4 < 16; ++d4) {
                float4 kk = *(const float4*)&Ks[j][d4 * 4];
                acc += qr[d4 * 4 + 0] * kk.x + qr[d4 * 4 + 1] * kk.y
                     + qr[d4 * 4 + 2] * kk.z + qr[d4 * 4 + 3] * kk.w;
            }
            if (Msk[j] == 0) acc = -1e9f;
            s[jj] = acc;
            mt = fmaxf(mt, acc);
        }
        float f = __expf(m - mt);
        l *= f;
        #pragma unroll
        for (int i = 0; i < 64; ++i) Ov[i] *= f;
        m = mt;
        #pragma unroll
        for (int jj = 0; jj < 16; ++jj) {
            int j = wid * 16 + jj;
            float p = __expf(s[jj] - m);
            l += p;
            #pragma unroll
            for (int d4 = 0; d4 < 16; ++d4) {
                float4 vv = *(const float4*)&Vs[j][d4 * 4];
                Ov[d4 * 4 + 0] += p * vv.x;
                Ov[d4 * 4 + 1] += p * vv.y;
                Ov[d4 * 4 + 2] += p * vv.z;
                Ov[d4 * 4 + 3] += p * vv.w;
            }
        }
        __syncthreads();
    }

    mred[wid][lane] = m;
    lred[wid][lane] = l;
    for (int i = tid; i < 64 * 65; i += 256) ((float*)Oacc)[i] = 0.f;
    __syncthreads();
    float gm = fmaxf(fmaxf(mred[0][lane], mred[1][lane]),
                     fmaxf(mred[2][lane], mred[3][lane]));
    float scale = __expf(m - gm);
    float lsum = lred[0][lane] * __expf(mred[0][lane] - gm)
               + lred[1][lane] * __expf(mred[1][lane] - gm)
               + lred[2][lane] * __expf(mred[2][lane] - gm)
               + lred[3][lane] * __expf(mred[3][lane] - gm);
    if (wid == 0) linv[lane] = (lsum > 0.f) ? (1.f / lsum) : 0.f;
    for (int w = 0; w < 4; ++w) {
        if (wid == w) {
            #pragma unroll
            for (int i = 0; i < 64; ++i) Oacc[lane][i] += scale * Ov[i];
        }
        __syncthreads();
    }

    {
        const int qi = tid >> 2, d0 = (tid & 3) * 16;
        float inv = linv[qi];
        bf16* op = out + ((size_t)(b * S + q0 + qi)) * D + h * hd + d0;
        #pragma unroll
        for (int i = 0; i < 16; ++i) op[i] = __float2bfloat16(Oacc[qi][d0 + i] * inv);
    }
}

extern "C" void kernel_launch(void* const* d_in, const int* in_sizes, int n_in,
                              void* d_out, int out_size, void* d_ws, size_t ws_size,
                              hipStream_t stream) {
    const int B = 2, S = 2048, D = 1024, H = 16, hd = 64, F = 4096;
    const int M = B * S;  // 4096

    const float* x   = (const float*)d_in[0];
    const int*   mask= (const int*)  d_in[1];
    const float* wq  = (const float*)d_in[2];
    const float* bq  = (const float*)d_in[3];
    const float* wk  = (const float*)d_in[4];
    const float* bk  = (const float*)d_in[5];
    const float* wv  = (const float*)d_in[6];
    const float* bv  = (const float*)d_in[7];
    const float* wo  = (const float*)d_in[8];
    const float* bo  = (const float*)d_in[9];
    const float* g1  = (const float*)d_in[10];
    const float* be1 = (const float*)d_in[11];
    const float* g2  = (const float*)d_in[12];
    const float* be2 = (const float*)d_in[13];
    const float* w1  = (const float*)d_in[14];
    const float* bf1 = (const float*)d_in[15];
    const float* w2  = (const float*)d_in[16];
    const float* bf2 = (const float*)d_in[17];
    float* out = (float*)d_out;

    char* ws = (char*)d_ws;
    const size_t MB = 1024 * 1024;
    bf16* wqT = (bf16*)(ws + 0 * MB);    // [1024,1024]
    bf16* wkT = (bf16*)(ws + 2 * MB);
    bf16* wvT = (bf16*)(ws + 4 * MB);
    bf16* woT = (bf16*)(ws + 6 * MB);
    bf16* w1T = (bf16*)(ws + 8 * MB);    // [4096,1024]
    bf16* w2T = (bf16*)(ws + 16 * MB);   // [1024,4096]
    bf16* xn  = (bf16*)(ws + 24 * MB);
    bf16* qb  = (bf16*)(ws + 32 * MB);
    bf16* kb  = (bf16*)(ws + 40 * MB);
    bf16* vb  = (bf16*)(ws + 48 * MB);
    bf16* att = xn;    // reuse
    bf16* x2  = qb;    // reuse
    bf16* xn2 = kb;    // reuse
    bf16* hid = vb;    // reuse; extends past 56MB if ws_size allows

    // FFN chunk rows: full if hid [4096,4096]bf16=32MB fits at 48MB offset.
    int CH = 1024;
    if (ws_size >= 80 * MB) CH = 4096;
    else if (ws_size >= 64 * MB) CH = 2048;

    // weight transposes (bf16 cast), ~15 us total
    transpose_cast<<<dim3(D / 32, D / 32), 256, 0, stream>>>(wq, wqT, D, D);
    transpose_cast<<<dim3(D / 32, D / 32), 256, 0, stream>>>(wk, wkT, D, D);
    transpose_cast<<<dim3(D / 32, D / 32), 256, 0, stream>>>(wv, wvT, D, D);
    transpose_cast<<<dim3(D / 32, D / 32), 256, 0, stream>>>(wo, woT, D, D);
    transpose_cast<<<dim3(F / 32, D / 32), 256, 0, stream>>>(w1, w1T, D, F);
    transpose_cast<<<dim3(D / 32, F / 32), 256, 0, stream>>>(w2, w2T, F, D);

    // LN1
    ln_kernel<float><<<M, 256, 0, stream>>>(x, g1, be1, xn, D);

    // QKV (MFMA)
    dim3 gDD(D / 128, M / 128);
    gemm_mfma<bf16, float, false, false><<<gDD, 256, 0, stream>>>(xn, wqT, bq, (const float*)nullptr, qb, M, D, D);
    gemm_mfma<bf16, float, false, false><<<gDD, 256, 0, stream>>>(xn, wkT, bk, (const float*)nullptr, kb, M, D, D);
    gemm_mfma<bf16, float, false, false><<<gDD, 256, 0, stream>>>(xn, wvT, bv, (const float*)nullptr, vb, M, D, D);

    // attention
    attn_flash<<<dim3(S / 64, H, B), 256, 0, stream>>>(qb, kb, vb, mask, att, B, S, H, hd);

    // out-proj + residual(x fp32) -> x2 bf16
    gemm_mfma<bf16, float, false, true><<<gDD, 256, 0, stream>>>(att, woT, bo, x, x2, M, D, D);

    // LN2
    ln_kernel<bf16><<<M, 256, 0, stream>>>(x2, g2, be2, xn2, D);

    // FFN (chunked rows, hid at 48MB)
    for (int c = 0; c < M / CH; ++c) {
        const size_t roff = (size_t)c * CH;
        gemm_mfma<bf16, float, true, false><<<dim3(F / 128, CH / 128), 256, 0, stream>>>(
            xn2 + roff * D, w1T, bf1, (const float*)nullptr, hid, CH, F, D);
        gemm_mfma<float, bf16, false, true><<<dim3(D / 128, CH / 128), 256, 0, stream>>>(
            hid, w2T, bf2, x2 + roff * D, out + roff * D, CH, D, F);
    }
}

// Round 5
// 571.637 us; speedup vs baseline: 4.7470x; 2.1195x over previous
//
#include <hip/hip_runtime.h>
#include <hip/hip_bf16.h>

// Transformer block: LN1 -> QKV -> MHA(16 heads, hd=64) -> out-proj + resid
//                    -> LN2 -> FFN(4x, ReLU) + resid
// B=2, S=2048, D=1024, H=16, hd=64, F=4096. M = B*S = 4096.
// fp32 buffers in/out; bf16 intermediates (fp32 accumulation).
//
// Round 5: MFMA flash attention replaces the scalar attn (was 889 us, 73% of
// runtime, VALU-bound with spills). One block = (64 q-rows, h, b); wave w owns
// q-strip [w*16,w*16+16) so softmax state is wave-private. Per KV-tile (64):
//   QK^T: 8x mfma_16x16x32_bf16 (Q A-frags in regs, K B-frags from LDS)
//   softmax in C/D layout, shfl_xor reductions within 16-lane groups
//   P -> per-wave LDS buffer -> A-frags (m120 round-trip); V staged transposed
//   PV: 8x mfma accumulating O in C/D layout
// LDS tiles padded to stride 66 elems (132B) to break power-of-2 bank aliasing.
// GEMM/LN/transpose pipeline unchanged from round 4.

using bf16 = __hip_bfloat16;
typedef short bf16x8 __attribute__((ext_vector_type(8)));
typedef float f32x4 __attribute__((ext_vector_type(4)));

__device__ __forceinline__ float toF(float v) { return v; }
__device__ __forceinline__ float toF(bf16 v) { return __bfloat162float(v); }
__device__ __forceinline__ void storeF(float* p, float v) { *p = v; }
__device__ __forceinline__ void storeF(bf16* p, float v) { *p = __float2bfloat16(v); }

__device__ __forceinline__ float waveReduceSum(float v) {
    #pragma unroll
    for (int o = 32; o > 0; o >>= 1) v += __shfl_down(v, o, 64);
    return v;
}

// async global->LDS, 16B per lane; lptr must be wave-uniform, HW scatters
// lane l to lptr + l*16.
__device__ __forceinline__ void async16(const bf16* g, bf16* l) {
    __builtin_amdgcn_global_load_lds(
        (const __attribute__((address_space(1))) unsigned int*)g,
        (__attribute__((address_space(3))) unsigned int*)l,
        16, 0, 0);
}

// ---------------- weight transpose + cast: fp32 [R,C] -> bf16 [C,R] --------
__global__ __launch_bounds__(256) void transpose_cast(const float* __restrict__ in,
                                                      bf16* __restrict__ outT,
                                                      int R, int C) {
    __shared__ float t[32][33];
    const int c0 = blockIdx.x * 32, r0 = blockIdx.y * 32;
    const int lx = threadIdx.x & 31, ly = threadIdx.x >> 5;  // 32 x 8
    #pragma unroll
    for (int i = 0; i < 32; i += 8)
        t[ly + i][lx] = in[(size_t)(r0 + ly + i) * C + c0 + lx];
    __syncthreads();
    #pragma unroll
    for (int i = 0; i < 32; i += 8)
        outT[(size_t)(c0 + ly + i) * R + r0 + lx] = __float2bfloat16(t[lx][ly + i]);
}

// ---------------- LayerNorm: InT x -> bf16 out ----------------
template <typename InT>
__global__ __launch_bounds__(256) void ln_kernel(const InT* __restrict__ x,
                                                 const float* __restrict__ g,
                                                 const float* __restrict__ b,
                                                 bf16* __restrict__ out, int D) {
    const int row = blockIdx.x;
    const InT* xr = x + (size_t)row * D;
    float s = 0.f, s2 = 0.f;
    for (int i = threadIdx.x; i < D; i += 256) {
        float v = toF(xr[i]);
        s += v; s2 += v * v;
    }
    __shared__ float ws[4], ws2[4];
    int lane = threadIdx.x & 63, wid = threadIdx.x >> 6;
    s = waveReduceSum(s); s2 = waveReduceSum(s2);
    if (lane == 0) { ws[wid] = s; ws2[wid] = s2; }
    __syncthreads();
    float ts = ws[0] + ws[1] + ws[2] + ws[3];
    float ts2 = ws2[0] + ws2[1] + ws2[2] + ws2[3];
    float mean = ts / D;
    float var = ts2 / D - mean * mean;
    float rstd = rsqrtf(var + 1e-5f);
    bf16* outr = out + (size_t)row * D;
    for (int i = threadIdx.x; i < D; i += 256) {
        float v = (toF(xr[i]) - mean) * rstd * g[i] + b[i];
        outr[i] = __float2bfloat16(v);
    }
}

// ---------------- MFMA GEMM: C = act(A @ BT^T + bias) [+ resid] ------------
template <typename OutT, typename ResidT, bool RELU, bool HAS_RESID>
__global__ __launch_bounds__(256) void gemm_mfma(const bf16* __restrict__ A,
                                                 const bf16* __restrict__ BT,
                                                 const float* __restrict__ bias,
                                                 const ResidT* __restrict__ resid,
                                                 OutT* __restrict__ C,
                                                 int M, int N, int K) {
    constexpr int BK = 32;
    __shared__ bf16 As[128][BK];
    __shared__ bf16 Bs[128][BK];
    const int tid = threadIdx.x, lane = tid & 63, wid = tid >> 6;
    const int m0 = blockIdx.y * 128, n0 = blockIdx.x * 128;
    const int wm = (wid >> 1) * 64, wn = (wid & 1) * 64;

    f32x4 acc[4][4] = {};

    const int srow = wid * 16 + (lane >> 2);
    const int scol = (lane & 3) * 8;
    const size_t aBase0 = (size_t)(m0 + srow) * K + scol;
    const size_t aBase1 = (size_t)(m0 + 64 + srow) * K + scol;
    const size_t bBase0 = (size_t)(n0 + srow) * K + scol;
    const size_t bBase1 = (size_t)(n0 + 64 + srow) * K + scol;

    const int fr = lane & 15;
    const int fk = (lane >> 4) * 8;

    for (int k0 = 0; k0 < K; k0 += BK) {
        async16(A + aBase0 + k0, &As[wid * 16][0]);
        async16(A + aBase1 + k0, &As[64 + wid * 16][0]);
        async16(BT + bBase0 + k0, &Bs[wid * 16][0]);
        async16(BT + bBase1 + k0, &Bs[64 + wid * 16][0]);
        __syncthreads();

        bf16x8 aF[4], bF[4];
        #pragma unroll
        for (int i = 0; i < 4; ++i)
            aF[i] = *(const bf16x8*)&As[wm + i * 16 + fr][fk];
        #pragma unroll
        for (int j = 0; j < 4; ++j)
            bF[j] = *(const bf16x8*)&Bs[wn + j * 16 + fr][fk];
        #pragma unroll
        for (int i = 0; i < 4; ++i)
            #pragma unroll
            for (int j = 0; j < 4; ++j)
                acc[i][j] = __builtin_amdgcn_mfma_f32_16x16x32_bf16(
                    aF[i], bF[j], acc[i][j], 0, 0, 0);
        __syncthreads();
    }

    const int col_l = lane & 15, row_l = (lane >> 4) * 4;
    #pragma unroll
    for (int j = 0; j < 4; ++j) {
        const int col = n0 + wn + j * 16 + col_l;
        const float bv = bias[col];
        #pragma unroll
        for (int i = 0; i < 4; ++i) {
            #pragma unroll
            for (int r = 0; r < 4; ++r) {
                const int row = m0 + wm + i * 16 + row_l + r;
                float v = acc[i][j][r] + bv;
                if (RELU) v = fmaxf(v, 0.f);
                if (HAS_RESID) v += toF(resid[(size_t)row * N + col]);
                storeF(&C[(size_t)row * N + col], v);
            }
        }
    }
}

// ---------------- MFMA flash attention ----------------
// grid (S/64, H, B), block 256 = 4 waves; wave w owns q-rows [w*16, w*16+16).
__global__ __launch_bounds__(256) void attn_mfma(const bf16* __restrict__ q,
                                                 const bf16* __restrict__ k,
                                                 const bf16* __restrict__ v,
                                                 const int* __restrict__ mask,
                                                 bf16* __restrict__ out,
                                                 int B, int S, int H, int hd) {
    const int q0 = blockIdx.x * 64;
    const int h = blockIdx.y, b = blockIdx.z;
    const int D = 1024;
    const int tid = threadIdx.x, lane = tid & 63, wid = tid >> 6;
    const int n = lane & 15, kg = lane >> 4;   // fragment col / k-group

    // stride 66 elems (132 B = 33 dwords) -> odd dword stride kills
    // power-of-2 bank aliasing on transposed/fragment access patterns.
    __shared__ bf16 Ks[64][66];        // K tile  [j][d]
    __shared__ bf16 Vt[64][66];        // V tile transposed [d][j]
    __shared__ bf16 Plds[4][16][66];   // per-wave P [q_local][j]
    __shared__ int  Msk[64];

    // Q A-frags (rows q0+wid*16+n), 2 k-steps, pre-loaded once
    bf16x8 qf[2];
    {
        const bf16* qp = q + ((size_t)(b * S + q0 + wid * 16 + n)) * D + h * 64 + kg * 8;
        union { uint4 u; bf16x8 v; } c0, c1;
        c0.u = *(const uint4*)qp;
        c1.u = *(const uint4*)(qp + 32);
        qf[0] = c0.v; qf[1] = c1.v;
    }

    f32x4 acc_o[4] = {};               // O in C/D layout, dt = d-tile
    float m_r[4] = {-1e30f, -1e30f, -1e30f, -1e30f};
    float l_r[4] = {0.f, 0.f, 0.f, 0.f};

    const int sr = tid >> 2;           // staging row j (0..63)
    const int sc = (tid & 3) * 16;     // staging col d0
    const bf16* kbase = k + (size_t)(b * S) * D + h * 64;
    const bf16* vbase = v + (size_t)(b * S) * D + h * 64;

    for (int j0 = 0; j0 < S; j0 += 64) {
        __syncthreads();   // previous iteration's Ks/Vt reads done
        {
            const bf16* kp = kbase + (size_t)(j0 + sr) * D + sc;
            uint4 ka = *(const uint4*)kp;
            uint4 kbv = *(const uint4*)(kp + 8);
            uint* kd = (uint*)((char*)&Ks[0][0] + sr * 132 + sc * 2);
            kd[0] = ka.x; kd[1] = ka.y; kd[2] = ka.z; kd[3] = ka.w;
            kd[4] = kbv.x; kd[5] = kbv.y; kd[6] = kbv.z; kd[7] = kbv.w;

            const bf16* vp = vbase + (size_t)(j0 + sr) * D + sc;
            union { uint4 u[2]; unsigned short s[16]; } vv;
            vv.u[0] = *(const uint4*)vp;
            vv.u[1] = *(const uint4*)(vp + 8);
            #pragma unroll
            for (int i = 0; i < 16; ++i)
                *((unsigned short*)((char*)&Vt[0][0] + (size_t)(sc + i) * 132 + sr * 2)) = vv.s[i];

            if (tid < 64) Msk[tid] = mask[b * S + j0 + tid];
        }
        __syncthreads();

        // ---- QK^T: S-tile st[jt], rows q=kg*4+r, cols j=jt*16+n ----
        f32x4 st[4] = {};
        #pragma unroll
        for (int ks = 0; ks < 2; ++ks) {
            #pragma unroll
            for (int jt = 0; jt < 4; ++jt) {
                union { uint u[4]; bf16x8 v; } bf;
                const uint* bp = (const uint*)((const char*)&Ks[0][0]
                                 + (size_t)(jt * 16 + n) * 132 + ks * 64 + kg * 16);
                bf.u[0] = bp[0]; bf.u[1] = bp[1]; bf.u[2] = bp[2]; bf.u[3] = bp[3];
                st[jt] = __builtin_amdgcn_mfma_f32_16x16x32_bf16(qf[ks], bf.v, st[jt], 0, 0, 0);
            }
        }

        int mk[4];
        #pragma unroll
        for (int jt = 0; jt < 4; ++jt) mk[jt] = Msk[jt * 16 + n];

        // ---- online softmax (per r = row within lane's 4 rows) ----
        #pragma unroll
        for (int r = 0; r < 4; ++r) {
            float mx = -1e30f;
            #pragma unroll
            for (int jt = 0; jt < 4; ++jt) {
                float s = st[jt][r] * 0.125f;           // 1/sqrt(64)
                if (mk[jt] == 0) s = -1e9f;
                st[jt][r] = s;
                mx = fmaxf(mx, s);
            }
            #pragma unroll
            for (int o = 1; o < 16; o <<= 1) mx = fmaxf(mx, __shfl_xor(mx, o, 64));
            float newm = fmaxf(m_r[r], mx);
            float alpha = __expf(m_r[r] - newm);
            m_r[r] = newm;
            float ls = 0.f;
            #pragma unroll
            for (int jt = 0; jt < 4; ++jt) {
                float p = __expf(st[jt][r] - newm);
                ls += p;
                Plds[wid][kg * 4 + r][jt * 16 + n] = __float2bfloat16(p);
            }
            #pragma unroll
            for (int o = 1; o < 16; o <<= 1) ls += __shfl_xor(ls, o, 64);
            l_r[r] = l_r[r] * alpha + ls;
            #pragma unroll
            for (int dt = 0; dt < 4; ++dt) acc_o[dt][r] *= alpha;
        }

        // P writes visible to all lanes of this wave before A-frag reads
        __asm__ volatile("s_waitcnt lgkmcnt(0)" ::: "memory");

        // ---- PV: O += P @ V  (A = P from Plds, B = Vt) ----
        #pragma unroll
        for (int ks = 0; ks < 2; ++ks) {
            union { uint u[4]; bf16x8 v; } af;
            const uint* ap = (const uint*)((const char*)&Plds[wid][0][0]
                             + (size_t)n * 132 + ks * 64 + kg * 16);
            af.u[0] = ap[0]; af.u[1] = ap[1]; af.u[2] = ap[2]; af.u[3] = ap[3];
            #pragma unroll
            for (int dt = 0; dt < 4; ++dt) {
                union { uint u[4]; bf16x8 v; } bf;
                const uint* bp = (const uint*)((const char*)&Vt[0][0]
                                 + (size_t)(dt * 16 + n) * 132 + ks * 64 + kg * 16);
                bf.u[0] = bp[0]; bf.u[1] = bp[1]; bf.u[2] = bp[2]; bf.u[3] = bp[3];
                acc_o[dt] = __builtin_amdgcn_mfma_f32_16x16x32_bf16(af.v, bf.v, acc_o[dt], 0, 0, 0);
            }
        }
    }

    // ---- epilogue: normalize and store ----
    #pragma unroll
    for (int r = 0; r < 4; ++r) {
        float inv = (l_r[r] > 0.f) ? (1.f / l_r[r]) : 0.f;
        bf16* op = out + ((size_t)(b * S + q0 + wid * 16 + kg * 4 + r)) * D + h * 64 + n;
        #pragma unroll
        for (int dt = 0; dt < 4; ++dt)
            op[dt * 16] = __float2bfloat16(acc_o[dt][r] * inv);
    }
}

extern "C" void kernel_launch(void* const* d_in, const int* in_sizes, int n_in,
                              void* d_out, int out_size, void* d_ws, size_t ws_size,
                              hipStream_t stream) {
    const int B = 2, S = 2048, D = 1024, H = 16, hd = 64, F = 4096;
    const int M = B * S;  // 4096

    const float* x   = (const float*)d_in[0];
    const int*   mask= (const int*)  d_in[1];
    const float* wq  = (const float*)d_in[2];
    const float* bq  = (const float*)d_in[3];
    const float* wk  = (const float*)d_in[4];
    const float* bk  = (const float*)d_in[5];
    const float* wv  = (const float*)d_in[6];
    const float* bv  = (const float*)d_in[7];
    const float* wo  = (const float*)d_in[8];
    const float* bo  = (const float*)d_in[9];
    const float* g1  = (const float*)d_in[10];
    const float* be1 = (const float*)d_in[11];
    const float* g2  = (const float*)d_in[12];
    const float* be2 = (const float*)d_in[13];
    const float* w1  = (const float*)d_in[14];
    const float* bf1 = (const float*)d_in[15];
    const float* w2  = (const float*)d_in[16];
    const float* bf2 = (const float*)d_in[17];
    float* out = (float*)d_out;

    char* ws = (char*)d_ws;
    const size_t MB = 1024 * 1024;
    bf16* wqT = (bf16*)(ws + 0 * MB);
    bf16* wkT = (bf16*)(ws + 2 * MB);
    bf16* wvT = (bf16*)(ws + 4 * MB);
    bf16* woT = (bf16*)(ws + 6 * MB);
    bf16* w1T = (bf16*)(ws + 8 * MB);
    bf16* w2T = (bf16*)(ws + 16 * MB);
    bf16* xn  = (bf16*)(ws + 24 * MB);
    bf16* qb  = (bf16*)(ws + 32 * MB);
    bf16* kb  = (bf16*)(ws + 40 * MB);
    bf16* vb  = (bf16*)(ws + 48 * MB);
    bf16* att = xn;
    bf16* x2  = qb;
    bf16* xn2 = kb;
    bf16* hid = vb;

    int CH = 1024;
    if (ws_size >= 80 * MB) CH = 4096;
    else if (ws_size >= 64 * MB) CH = 2048;

    transpose_cast<<<dim3(D / 32, D / 32), 256, 0, stream>>>(wq, wqT, D, D);
    transpose_cast<<<dim3(D / 32, D / 32), 256, 0, stream>>>(wk, wkT, D, D);
    transpose_cast<<<dim3(D / 32, D / 32), 256, 0, stream>>>(wv, wvT, D, D);
    transpose_cast<<<dim3(D / 32, D / 32), 256, 0, stream>>>(wo, woT, D, D);
    transpose_cast<<<dim3(F / 32, D / 32), 256, 0, stream>>>(w1, w1T, D, F);
    transpose_cast<<<dim3(D / 32, F / 32), 256, 0, stream>>>(w2, w2T, F, D);

    ln_kernel<float><<<M, 256, 0, stream>>>(x, g1, be1, xn, D);

    dim3 gDD(D / 128, M / 128);
    gemm_mfma<bf16, float, false, false><<<gDD, 256, 0, stream>>>(xn, wqT, bq, (const float*)nullptr, qb, M, D, D);
    gemm_mfma<bf16, float, false, false><<<gDD, 256, 0, stream>>>(xn, wkT, bk, (const float*)nullptr, kb, M, D, D);
    gemm_mfma<bf16, float, false, false><<<gDD, 256, 0, stream>>>(xn, wvT, bv, (const float*)nullptr, vb, M, D, D);

    attn_mfma<<<dim3(S / 64, H, B), 256, 0, stream>>>(qb, kb, vb, mask, att, B, S, H, hd);

    gemm_mfma<bf16, float, false, true><<<gDD, 256, 0, stream>>>(att, woT, bo, x, x2, M, D, D);

    ln_kernel<bf16><<<M, 256, 0, stream>>>(x2, g2, be2, xn2, D);

    for (int c = 0; c < M / CH; ++c) {
        const size_t roff = (size_t)c * CH;
        gemm_mfma<bf16, float, true, false><<<dim3(F / 128, CH / 128), 256, 0, stream>>>(
            xn2 + roff * D, w1T, bf1, (const float*)nullptr, hid, CH, F, D);
        gemm_mfma<float, bf16, false, true><<<dim3(D / 128, CH / 128), 256, 0, stream>>>(
            hid, w2T, bf2, x2 + roff * D, out + roff * D, CH, D, F);
    }
}

// Round 6
// 479.179 us; speedup vs baseline: 5.6629x; 1.1930x over previous
//
#include <hip/hip_runtime.h>
#include <hip/hip_bf16.h>

// Transformer block: LN1 -> QKV -> MHA(16 heads, hd=64) -> out-proj + resid
//                    -> LN2 -> FFN(4x, ReLU) + resid
// B=2, S=2048, D=1024, H=16, hd=64, F=4096. M = B*S = 4096.
// fp32 buffers in/out; bf16 intermediates (fp32 accumulation).
//
// Round 6:
//  (a) attention computes S^T = K@Q^T (swapped MFMA operands). Per-lane C/D
//      column = one q => softmax reductions are 2 shfl_xor; P^T lands directly
//      in mfma_f32_16x16x16_bf16 fragment layout => PV = V^T@P^T with P from
//      REGISTERS (no LDS round-trip, no lgkmcnt(0) drain). V staged to LDS as
//      pair-packed b32 (2-way conflicts = free). Mask as additive f32 bias.
//  (b) QKV fused into one GEMM (N=3072 -> 768 blocks = 3/CU vs 1/CU before),
//      3-section bias epilogue. attn reads qkv with row stride 3072.
//
// Workspace:
//   [0,6)MB  wqkvT bf16 [3072,1024]  (wq/wk/wv transposed sections)
//   [6,8)    woT, [8,16) w1T, [16,24) w2T
//   [24,32)  xn -> att reuse
//   [32,56)  qkv bf16 [4096,3072]; after attn: x2=[32,40), xn2=[40,48),
//            hid=[48,48+CH*8KB)

using bf16 = __hip_bfloat16;
typedef short bf16x8 __attribute__((ext_vector_type(8)));
typedef short bf16x4v __attribute__((ext_vector_type(4)));
typedef float f32x4 __attribute__((ext_vector_type(4)));

#if defined(__has_builtin)
#  if __has_builtin(__builtin_amdgcn_mfma_f32_16x16x16bf16_1k)
#    define HAVE_MFMA_K16 1
#  endif
#endif

__device__ __forceinline__ float toF(float v) { return v; }
__device__ __forceinline__ float toF(bf16 v) { return __bfloat162float(v); }
__device__ __forceinline__ void storeF(float* p, float v) { *p = v; }
__device__ __forceinline__ void storeF(bf16* p, float v) { *p = __float2bfloat16(v); }

__device__ __forceinline__ float waveReduceSum(float v) {
    #pragma unroll
    for (int o = 32; o > 0; o >>= 1) v += __shfl_down(v, o, 64);
    return v;
}

__device__ __forceinline__ void async16(const bf16* g, bf16* l) {
    __builtin_amdgcn_global_load_lds(
        (const __attribute__((address_space(1))) unsigned int*)g,
        (__attribute__((address_space(3))) unsigned int*)l,
        16, 0, 0);
}

__device__ __forceinline__ unsigned short bf16bits(float x) {
    union { bf16 h; unsigned short u; } e; e.h = __float2bfloat16(x);
    return e.u;
}

// ---------------- weight transpose + cast: fp32 [R,C] -> bf16 [C,R] --------
__global__ __launch_bounds__(256) void transpose_cast(const float* __restrict__ in,
                                                      bf16* __restrict__ outT,
                                                      int R, int C) {
    __shared__ float t[32][33];
    const int c0 = blockIdx.x * 32, r0 = blockIdx.y * 32;
    const int lx = threadIdx.x & 31, ly = threadIdx.x >> 5;
    #pragma unroll
    for (int i = 0; i < 32; i += 8)
        t[ly + i][lx] = in[(size_t)(r0 + ly + i) * C + c0 + lx];
    __syncthreads();
    #pragma unroll
    for (int i = 0; i < 32; i += 8)
        outT[(size_t)(c0 + ly + i) * R + r0 + lx] = __float2bfloat16(t[lx][ly + i]);
}

// ---------------- LayerNorm: InT x -> bf16 out ----------------
template <typename InT>
__global__ __launch_bounds__(256) void ln_kernel(const InT* __restrict__ x,
                                                 const float* __restrict__ g,
                                                 const float* __restrict__ b,
                                                 bf16* __restrict__ out, int D) {
    const int row = blockIdx.x;
    const InT* xr = x + (size_t)row * D;
    float s = 0.f, s2 = 0.f;
    for (int i = threadIdx.x; i < D; i += 256) {
        float v = toF(xr[i]);
        s += v; s2 += v * v;
    }
    __shared__ float ws[4], ws2[4];
    int lane = threadIdx.x & 63, wid = threadIdx.x >> 6;
    s = waveReduceSum(s); s2 = waveReduceSum(s2);
    if (lane == 0) { ws[wid] = s; ws2[wid] = s2; }
    __syncthreads();
    float ts = ws[0] + ws[1] + ws[2] + ws[3];
    float ts2 = ws2[0] + ws2[1] + ws2[2] + ws2[3];
    float mean = ts / D;
    float var = ts2 / D - mean * mean;
    float rstd = rsqrtf(var + 1e-5f);
    bf16* outr = out + (size_t)row * D;
    for (int i = threadIdx.x; i < D; i += 256) {
        float v = (toF(xr[i]) - mean) * rstd * g[i] + b[i];
        outr[i] = __float2bfloat16(v);
    }
}

// ---------------- MFMA GEMM: C = act(A @ BT^T + bias) [+ resid] ------------
// BIAS3: bias is three 1024-sections (bias/biasK/biasV) selected by col>>10.
template <typename OutT, typename ResidT, bool RELU, bool HAS_RESID, bool BIAS3>
__global__ __launch_bounds__(256) void gemm_mfma(const bf16* __restrict__ A,
                                                 const bf16* __restrict__ BT,
                                                 const float* __restrict__ bias,
                                                 const float* __restrict__ biasK,
                                                 const float* __restrict__ biasV,
                                                 const ResidT* __restrict__ resid,
                                                 OutT* __restrict__ C,
                                                 int M, int N, int K) {
    constexpr int BK = 32;
    __shared__ bf16 As[128][BK];
    __shared__ bf16 Bs[128][BK];
    const int tid = threadIdx.x, lane = tid & 63, wid = tid >> 6;
    const int m0 = blockIdx.y * 128, n0 = blockIdx.x * 128;
    const int wm = (wid >> 1) * 64, wn = (wid & 1) * 64;

    f32x4 acc[4][4] = {};

    const int srow = wid * 16 + (lane >> 2);
    const int scol = (lane & 3) * 8;
    const size_t aBase0 = (size_t)(m0 + srow) * K + scol;
    const size_t aBase1 = (size_t)(m0 + 64 + srow) * K + scol;
    const size_t bBase0 = (size_t)(n0 + srow) * K + scol;
    const size_t bBase1 = (size_t)(n0 + 64 + srow) * K + scol;

    const int fr = lane & 15;
    const int fk = (lane >> 4) * 8;

    for (int k0 = 0; k0 < K; k0 += BK) {
        async16(A + aBase0 + k0, &As[wid * 16][0]);
        async16(A + aBase1 + k0, &As[64 + wid * 16][0]);
        async16(BT + bBase0 + k0, &Bs[wid * 16][0]);
        async16(BT + bBase1 + k0, &Bs[64 + wid * 16][0]);
        __syncthreads();

        bf16x8 aF[4], bF[4];
        #pragma unroll
        for (int i = 0; i < 4; ++i)
            aF[i] = *(const bf16x8*)&As[wm + i * 16 + fr][fk];
        #pragma unroll
        for (int j = 0; j < 4; ++j)
            bF[j] = *(const bf16x8*)&Bs[wn + j * 16 + fr][fk];
        #pragma unroll
        for (int i = 0; i < 4; ++i)
            #pragma unroll
            for (int j = 0; j < 4; ++j)
                acc[i][j] = __builtin_amdgcn_mfma_f32_16x16x32_bf16(
                    aF[i], bF[j], acc[i][j], 0, 0, 0);
        __syncthreads();
    }

    const int col_l = lane & 15, row_l = (lane >> 4) * 4;
    #pragma unroll
    for (int j = 0; j < 4; ++j) {
        const int col = n0 + wn + j * 16 + col_l;
        float bvv;
        if (BIAS3) {
            const float* bp = (col < 1024) ? bias : ((col < 2048) ? biasK : biasV);
            bvv = bp[col & 1023];
        } else {
            bvv = bias[col];
        }
        #pragma unroll
        for (int i = 0; i < 4; ++i) {
            #pragma unroll
            for (int r = 0; r < 4; ++r) {
                const int row = m0 + wm + i * 16 + row_l + r;
                float v = acc[i][j][r] + bvv;
                if (RELU) v = fmaxf(v, 0.f);
                if (HAS_RESID) v += toF(resid[(size_t)row * N + col]);
                storeF(&C[(size_t)row * N + col], v);
            }
        }
    }
}

// ---------------- MFMA flash attention, S^T formulation --------------------
// grid (S/64, H, B), block 256 = 4 waves; wave w owns q-rows [w*16,w*16+16).
// qkv [M, LD=3072]: q at col 0, k at col 1024, v at col 2048; head h: +h*64.
#if HAVE_MFMA_K16
__global__ __launch_bounds__(256) void attn_mfma(const bf16* __restrict__ qkv,
                                                 const int* __restrict__ mask,
                                                 bf16* __restrict__ outp,
                                                 int B, int S, int LD) {
    const int q0 = blockIdx.x * 64;
    const int h = blockIdx.y, b = blockIdx.z;
    const int Do = 1024;
    const int tid = threadIdx.x, lane = tid & 63, wid = tid >> 6;
    const int n = lane & 15, kg = lane >> 4;

    __shared__ bf16 Ks[64][66];     // K tile [j][d], 132B rows (odd dword stride)
    __shared__ bf16 Vt[64][66];     // V^T tile [d][j]
    __shared__ float Mskf[64];      // additive mask bias

    // Q B-frags (B[k=d][n=q]), pre-scaled by 1/sqrt(64) (exact: 2^-3)
    bf16x8 qf[2];
    {
        const bf16* qp = qkv + ((size_t)(b * S + q0 + wid * 16 + n)) * LD + h * 64 + kg * 8;
        union { uint4 u; bf16x8 v; unsigned short s[8]; } c[2];
        c[0].u = *(const uint4*)qp;
        c[1].u = *(const uint4*)(qp + 32);
        #pragma unroll
        for (int t = 0; t < 2; ++t) {
            #pragma unroll
            for (int i = 0; i < 8; ++i) {
                union { float f; unsigned int u; } d;
                d.u = ((unsigned int)c[t].s[i]) << 16;
                c[t].s[i] = bf16bits(d.f * 0.125f);
            }
            qf[t] = c[t].v;
        }
    }

    f32x4 acc_o[4] = {};            // O^T: lane holds O[q=n][d=dt*16+kg*4+r]
    float m = -1e30f, l = 0.f;      // softmax state for q = wid*16+n (x4 kg-replicated)

    const int sr = tid >> 2, sc = (tid & 3) * 16;   // K staging: row, d-chunk
    const int jp = tid >> 3, dg = (tid & 7) * 8;    // V staging: j-pair, d-chunk
    const bf16* kbase = qkv + (size_t)(b * S) * LD + 1024 + h * 64;
    const bf16* vbase = qkv + (size_t)(b * S) * LD + 2048 + h * 64;

    for (int j0 = 0; j0 < S; j0 += 64) {
        __syncthreads();
        {
            const bf16* kp = kbase + (size_t)(j0 + sr) * LD + sc;
            uint4 ka = *(const uint4*)kp;
            uint4 kc = *(const uint4*)(kp + 8);
            uint* kd = (uint*)((char*)&Ks[0][0] + sr * 132 + sc * 2);
            kd[0] = ka.x; kd[1] = ka.y; kd[2] = ka.z; kd[3] = ka.w;
            kd[4] = kc.x; kd[5] = kc.y; kd[6] = kc.z; kd[7] = kc.w;

            // V: 2 j-rows x 8 d, write pair-packed b32 into Vt[d][j]
            const bf16* vp = vbase + (size_t)(j0 + 2 * jp) * LD + dg;
            union { uint4 u; unsigned short s[8]; } va, vc;
            va.u = *(const uint4*)vp;
            vc.u = *(const uint4*)(vp + LD);
            #pragma unroll
            for (int i = 0; i < 8; ++i) {
                unsigned int pk = (unsigned int)va.s[i] | ((unsigned int)vc.s[i] << 16);
                *(unsigned int*)((char*)&Vt[0][0] + (size_t)(dg + i) * 132 + jp * 4) = pk;
            }
            if (tid < 64) Mskf[tid] = (mask[b * S + j0 + tid] == 0) ? -1e9f : 0.f;
        }
        __syncthreads();

        // ---- S^T = K @ Q^T : st[jt], lane holds S^T[j=jt*16+kg*4+r][q=n] ----
        f32x4 st[4] = {};
        #pragma unroll
        for (int ks = 0; ks < 2; ++ks) {
            #pragma unroll
            for (int jt = 0; jt < 4; ++jt) {
                union { uint u[4]; bf16x8 v; } kf;
                const uint* bp = (const uint*)((const char*)&Ks[0][0]
                                 + (size_t)(jt * 16 + n) * 132 + ks * 64 + kg * 16);
                kf.u[0] = bp[0]; kf.u[1] = bp[1]; kf.u[2] = bp[2]; kf.u[3] = bp[3];
                st[jt] = __builtin_amdgcn_mfma_f32_16x16x32_bf16(kf.v, qf[ks], st[jt], 0, 0, 0);
            }
        }

        // ---- online softmax over j (per-lane state, 2 shfls per reduction) --
        float mx = m;
        #pragma unroll
        for (int jt = 0; jt < 4; ++jt) {
            f32x4 mb = *(const f32x4*)&Mskf[jt * 16 + kg * 4];
            #pragma unroll
            for (int r = 0; r < 4; ++r) {
                st[jt][r] += mb[r];
                mx = fmaxf(mx, st[jt][r]);
            }
        }
        mx = fmaxf(mx, __shfl_xor(mx, 16, 64));
        mx = fmaxf(mx, __shfl_xor(mx, 32, 64));
        float alpha = __expf(m - mx);
        m = mx;
        float ls = 0.f;
        bf16x4v pf[4];
        #pragma unroll
        for (int jt = 0; jt < 4; ++jt) {
            union { unsigned short s[4]; bf16x4v v; } pk;
            #pragma unroll
            for (int r = 0; r < 4; ++r) {
                float p = __expf(st[jt][r] - m);
                ls += p;
                pk.s[r] = bf16bits(p);
            }
            pf[jt] = pk.v;
        }
        ls += __shfl_xor(ls, 16, 64);
        ls += __shfl_xor(ls, 32, 64);
        l = l * alpha + ls;
        #pragma unroll
        for (int dt = 0; dt < 4; ++dt)
            #pragma unroll
            for (int r = 0; r < 4; ++r) acc_o[dt][r] *= alpha;

        // ---- O^T += V^T @ P^T  (A = V^T from Vt, B = P^T from registers) ----
        #pragma unroll
        for (int jt = 0; jt < 4; ++jt) {
            #pragma unroll
            for (int dt = 0; dt < 4; ++dt) {
                union { uint u[2]; bf16x4v v; } vf;
                const uint* vpp = (const uint*)((const char*)&Vt[0][0]
                                  + (size_t)(dt * 16 + n) * 132 + jt * 32 + kg * 8);
                vf.u[0] = vpp[0]; vf.u[1] = vpp[1];
                acc_o[dt] = __builtin_amdgcn_mfma_f32_16x16x16bf16_1k(
                    vf.v, pf[jt], acc_o[dt], 0, 0, 0);
            }
        }
    }

    // ---- epilogue: lane writes q-row (wid*16+n), 4 consecutive d per dt ----
    float inv = (l > 0.f) ? (1.f / l) : 0.f;
    bf16* op = outp + ((size_t)(b * S + q0 + wid * 16 + n)) * Do + h * 64;
    #pragma unroll
    for (int dt = 0; dt < 4; ++dt) {
        union { unsigned short s[4]; uint2 u; } w;
        #pragma unroll
        for (int r = 0; r < 4; ++r) w.s[r] = bf16bits(acc_o[dt][r] * inv);
        *(uint2*)(op + dt * 16 + kg * 4) = w.u;
    }
}
#else
// Fallback: round-5 kernel adapted to strided qkv layout.
__global__ __launch_bounds__(256) void attn_mfma(const bf16* __restrict__ qkv,
                                                 const int* __restrict__ mask,
                                                 bf16* __restrict__ outp,
                                                 int B, int S, int LD) {
    const int q0 = blockIdx.x * 64;
    const int h = blockIdx.y, b = blockIdx.z;
    const int Do = 1024;
    const int tid = threadIdx.x, lane = tid & 63, wid = tid >> 6;
    const int n = lane & 15, kg = lane >> 4;

    __shared__ bf16 Ks[64][66];
    __shared__ bf16 Vt[64][66];
    __shared__ bf16 Plds[4][16][66];
    __shared__ int  Msk[64];

    bf16x8 qf[2];
    {
        const bf16* qp = qkv + ((size_t)(b * S + q0 + wid * 16 + n)) * LD + h * 64 + kg * 8;
        union { uint4 u; bf16x8 v; } c0, c1;
        c0.u = *(const uint4*)qp;
        c1.u = *(const uint4*)(qp + 32);
        qf[0] = c0.v; qf[1] = c1.v;
    }

    f32x4 acc_o[4] = {};
    float m_r[4] = {-1e30f, -1e30f, -1e30f, -1e30f};
    float l_r[4] = {0.f, 0.f, 0.f, 0.f};

    const int sr = tid >> 2;
    const int sc = (tid & 3) * 16;
    const bf16* kbase = qkv + (size_t)(b * S) * LD + 1024 + h * 64;
    const bf16* vbase = qkv + (size_t)(b * S) * LD + 2048 + h * 64;

    for (int j0 = 0; j0 < S; j0 += 64) {
        __syncthreads();
        {
            const bf16* kp = kbase + (size_t)(j0 + sr) * LD + sc;
            uint4 ka = *(const uint4*)kp;
            uint4 kbv = *(const uint4*)(kp + 8);
            uint* kd = (uint*)((char*)&Ks[0][0] + sr * 132 + sc * 2);
            kd[0] = ka.x; kd[1] = ka.y; kd[2] = ka.z; kd[3] = ka.w;
            kd[4] = kbv.x; kd[5] = kbv.y; kd[6] = kbv.z; kd[7] = kbv.w;

            const bf16* vp = vbase + (size_t)(j0 + sr) * LD + sc;
            union { uint4 u[2]; unsigned short s[16]; } vv;
            vv.u[0] = *(const uint4*)vp;
            vv.u[1] = *(const uint4*)(vp + 8);
            #pragma unroll
            for (int i = 0; i < 16; ++i)
                *((unsigned short*)((char*)&Vt[0][0] + (size_t)(sc + i) * 132 + sr * 2)) = vv.s[i];

            if (tid < 64) Msk[tid] = mask[b * S + j0 + tid];
        }
        __syncthreads();

        f32x4 st[4] = {};
        #pragma unroll
        for (int ks = 0; ks < 2; ++ks) {
            #pragma unroll
            for (int jt = 0; jt < 4; ++jt) {
                union { uint u[4]; bf16x8 v; } bf;
                const uint* bp = (const uint*)((const char*)&Ks[0][0]
                                 + (size_t)(jt * 16 + n) * 132 + ks * 64 + kg * 16);
                bf.u[0] = bp[0]; bf.u[1] = bp[1]; bf.u[2] = bp[2]; bf.u[3] = bp[3];
                st[jt] = __builtin_amdgcn_mfma_f32_16x16x32_bf16(qf[ks], bf.v, st[jt], 0, 0, 0);
            }
        }

        int mk[4];
        #pragma unroll
        for (int jt = 0; jt < 4; ++jt) mk[jt] = Msk[jt * 16 + n];

        #pragma unroll
        for (int r = 0; r < 4; ++r) {
            float mx = -1e30f;
            #pragma unroll
            for (int jt = 0; jt < 4; ++jt) {
                float s = st[jt][r] * 0.125f;
                if (mk[jt] == 0) s = -1e9f;
                st[jt][r] = s;
                mx = fmaxf(mx, s);
            }
            #pragma unroll
            for (int o = 1; o < 16; o <<= 1) mx = fmaxf(mx, __shfl_xor(mx, o, 64));
            float newm = fmaxf(m_r[r], mx);
            float alpha = __expf(m_r[r] - newm);
            m_r[r] = newm;
            float ls = 0.f;
            #pragma unroll
            for (int jt = 0; jt < 4; ++jt) {
                float p = __expf(st[jt][r] - newm);
                ls += p;
                Plds[wid][kg * 4 + r][jt * 16 + n] = __float2bfloat16(p);
            }
            #pragma unroll
            for (int o = 1; o < 16; o <<= 1) ls += __shfl_xor(ls, o, 64);
            l_r[r] = l_r[r] * alpha + ls;
            #pragma unroll
            for (int dt = 0; dt < 4; ++dt) acc_o[dt][r] *= alpha;
        }

        __asm__ volatile("s_waitcnt lgkmcnt(0)" ::: "memory");

        #pragma unroll
        for (int ks = 0; ks < 2; ++ks) {
            union { uint u[4]; bf16x8 v; } af;
            const uint* ap = (const uint*)((const char*)&Plds[wid][0][0]
                             + (size_t)n * 132 + ks * 64 + kg * 16);
            af.u[0] = ap[0]; af.u[1] = ap[1]; af.u[2] = ap[2]; af.u[3] = ap[3];
            #pragma unroll
            for (int dt = 0; dt < 4; ++dt) {
                union { uint u[4]; bf16x8 v; } bf;
                const uint* bp = (const uint*)((const char*)&Vt[0][0]
                                 + (size_t)(dt * 16 + n) * 132 + ks * 64 + kg * 16);
                bf.u[0] = bp[0]; bf.u[1] = bp[1]; bf.u[2] = bp[2]; bf.u[3] = bp[3];
                acc_o[dt] = __builtin_amdgcn_mfma_f32_16x16x32_bf16(af.v, bf.v, acc_o[dt], 0, 0, 0);
            }
        }
    }

    #pragma unroll
    for (int r = 0; r < 4; ++r) {
        float inv = (l_r[r] > 0.f) ? (1.f / l_r[r]) : 0.f;
        bf16* op = outp + ((size_t)(b * S + q0 + wid * 16 + kg * 4 + r)) * Do + h * 64 + n;
        #pragma unroll
        for (int dt = 0; dt < 4; ++dt)
            op[dt * 16] = __float2bfloat16(acc_o[dt][r] * inv);
    }
}
#endif

extern "C" void kernel_launch(void* const* d_in, const int* in_sizes, int n_in,
                              void* d_out, int out_size, void* d_ws, size_t ws_size,
                              hipStream_t stream) {
    const int B = 2, S = 2048, D = 1024, H = 16, F = 4096;
    const int M = B * S;  // 4096

    const float* x   = (const float*)d_in[0];
    const int*   mask= (const int*)  d_in[1];
    const float* wq  = (const float*)d_in[2];
    const float* bq  = (const float*)d_in[3];
    const float* wk  = (const float*)d_in[4];
    const float* bk  = (const float*)d_in[5];
    const float* wv  = (const float*)d_in[6];
    const float* bv  = (const float*)d_in[7];
    const float* wo  = (const float*)d_in[8];
    const float* bo  = (const float*)d_in[9];
    const float* g1  = (const float*)d_in[10];
    const float* be1 = (const float*)d_in[11];
    const float* g2  = (const float*)d_in[12];
    const float* be2 = (const float*)d_in[13];
    const float* w1  = (const float*)d_in[14];
    const float* bf1 = (const float*)d_in[15];
    const float* w2  = (const float*)d_in[16];
    const float* bf2 = (const float*)d_in[17];
    float* out = (float*)d_out;

    char* ws = (char*)d_ws;
    const size_t MB = 1024 * 1024;
    bf16* wqkvT = (bf16*)(ws + 0 * MB);            // [3072,1024]
    bf16* woT   = (bf16*)(ws + 6 * MB);
    bf16* w1T   = (bf16*)(ws + 8 * MB);
    bf16* w2T   = (bf16*)(ws + 16 * MB);
    bf16* xn    = (bf16*)(ws + 24 * MB);
    bf16* qkv   = (bf16*)(ws + 32 * MB);           // [4096,3072]
    bf16* att   = xn;                              // reuse
    bf16* x2    = (bf16*)(ws + 32 * MB);           // qkv q-section reuse
    bf16* xn2   = (bf16*)(ws + 40 * MB);           // qkv k-section reuse
    bf16* hid   = (bf16*)(ws + 48 * MB);           // qkv v-section reuse +

    int CH = 1024;
    if (ws_size >= 80 * MB) CH = 4096;
    else if (ws_size >= 64 * MB) CH = 2048;

    // weight transposes (wq/wk/wv into contiguous wqkvT sections)
    transpose_cast<<<dim3(D / 32, D / 32), 256, 0, stream>>>(wq, wqkvT, D, D);
    transpose_cast<<<dim3(D / 32, D / 32), 256, 0, stream>>>(wk, wqkvT + (size_t)1024 * 1024, D, D);
    transpose_cast<<<dim3(D / 32, D / 32), 256, 0, stream>>>(wv, wqkvT + (size_t)2048 * 1024, D, D);
    transpose_cast<<<dim3(D / 32, D / 32), 256, 0, stream>>>(wo, woT, D, D);
    transpose_cast<<<dim3(F / 32, D / 32), 256, 0, stream>>>(w1, w1T, D, F);
    transpose_cast<<<dim3(D / 32, F / 32), 256, 0, stream>>>(w2, w2T, F, D);

    // LN1
    ln_kernel<float><<<M, 256, 0, stream>>>(x, g1, be1, xn, D);

    // fused QKV GEMM: [M,1024] @ [1024,3072] -> qkv [M,3072]
    gemm_mfma<bf16, float, false, false, true><<<dim3(3072 / 128, M / 128), 256, 0, stream>>>(
        xn, wqkvT, bq, bk, bv, (const float*)nullptr, qkv, M, 3072, D);

    // attention (strided qkv input)
    attn_mfma<<<dim3(S / 64, H, B), 256, 0, stream>>>(qkv, mask, att, B, S, 3072);

    // out-proj + residual(x fp32) -> x2 bf16
    gemm_mfma<bf16, float, false, true, false><<<dim3(D / 128, M / 128), 256, 0, stream>>>(
        att, woT, bo, nullptr, nullptr, x, x2, M, D, D);

    // LN2
    ln_kernel<bf16><<<M, 256, 0, stream>>>(x2, g2, be2, xn2, D);

    // FFN (chunked rows)
    for (int c = 0; c < M / CH; ++c) {
        const size_t roff = (size_t)c * CH;
        gemm_mfma<bf16, float, true, false, false><<<dim3(F / 128, CH / 128), 256, 0, stream>>>(
            xn2 + roff * D, w1T, bf1, nullptr, nullptr, (const float*)nullptr, hid, CH, F, D);
        gemm_mfma<float, bf16, false, true, false><<<dim3(D / 128, CH / 128), 256, 0, stream>>>(
            hid, w2T, bf2, nullptr, nullptr, x2 + roff * D, out + roff * D, CH, D, F);
    }
}

// Round 7
// 443.384 us; speedup vs baseline: 6.1201x; 1.0807x over previous
//
#include <hip/hip_runtime.h>
#include <hip/hip_bf16.h>

// Transformer block: LN1 -> QKV -> MHA(16 heads, hd=64) -> out-proj + resid
//                    -> LN2 -> FFN(4x, ReLU) + resid
// B=2, S=2048, D=1024, H=16, hd=64, F=4096. M = B*S = 4096.
// fp32 buffers in/out; bf16 intermediates (fp32 accumulation).
//
// Round 7:
//  (a) BM=64 GEMM tile variant for N=1024 GEMMs (out-proj, FFN-down):
//      512 blocks = 2/CU instead of 256 = 1/CU (barrier drain was fully
//      exposed at 1 block/CU).
//  (b) residual carrier x2 lives in d_out as fp32 (frees 8MB, better
//      accuracy); FFN runs full-M when ws_size >= 64MB (hid 32MB at
//      [24,56), xn2 at [56,64)), CH=2048 fallback otherwise.
//  (c) attention Vt stride 66 -> 68 elems (34 dwords): PV ds_read_b64 bank
//      becomes 2n+8jt+2kg => 2-way (free); V staging lanes re-assigned
//      (jp=tid&31) so packed b32 writes are conflict-free.
//
// Workspace:
//   [0,6)MB  wqkvT bf16 [3072,1024]; [6,8) woT; [8,16) w1T; [16,24) w2T
//   [24,32)  xn -> att reuse -> (dead after out-proj)
//   [32,56)  qkv bf16 [4096,3072] (dead after attn)
//   full-M:  hid [24,56) 32MB, xn2 [56,64)
//   chunked: xn2 [32,40), hid-half 16MB [40,56)

using bf16 = __hip_bfloat16;
typedef short bf16x8 __attribute__((ext_vector_type(8)));
typedef short bf16x4v __attribute__((ext_vector_type(4)));
typedef float f32x4 __attribute__((ext_vector_type(4)));

#if defined(__has_builtin)
#  if __has_builtin(__builtin_amdgcn_mfma_f32_16x16x16bf16_1k)
#    define HAVE_MFMA_K16 1
#  endif
#endif

__device__ __forceinline__ float toF(float v) { return v; }
__device__ __forceinline__ float toF(bf16 v) { return __bfloat162float(v); }
__device__ __forceinline__ void storeF(float* p, float v) { *p = v; }
__device__ __forceinline__ void storeF(bf16* p, float v) { *p = __float2bfloat16(v); }

__device__ __forceinline__ float waveReduceSum(float v) {
    #pragma unroll
    for (int o = 32; o > 0; o >>= 1) v += __shfl_down(v, o, 64);
    return v;
}

__device__ __forceinline__ void async16(const bf16* g, bf16* l) {
    __builtin_amdgcn_global_load_lds(
        (const __attribute__((address_space(1))) unsigned int*)g,
        (__attribute__((address_space(3))) unsigned int*)l,
        16, 0, 0);
}

__device__ __forceinline__ unsigned short bf16bits(float x) {
    union { bf16 h; unsigned short u; } e; e.h = __float2bfloat16(x);
    return e.u;
}

// ---------------- weight transpose + cast: fp32 [R,C] -> bf16 [C,R] --------
__global__ __launch_bounds__(256) void transpose_cast(const float* __restrict__ in,
                                                      bf16* __restrict__ outT,
                                                      int R, int C) {
    __shared__ float t[32][33];
    const int c0 = blockIdx.x * 32, r0 = blockIdx.y * 32;
    const int lx = threadIdx.x & 31, ly = threadIdx.x >> 5;
    #pragma unroll
    for (int i = 0; i < 32; i += 8)
        t[ly + i][lx] = in[(size_t)(r0 + ly + i) * C + c0 + lx];
    __syncthreads();
    #pragma unroll
    for (int i = 0; i < 32; i += 8)
        outT[(size_t)(c0 + ly + i) * R + r0 + lx] = __float2bfloat16(t[lx][ly + i]);
}

// ---------------- LayerNorm: InT x -> bf16 out ----------------
template <typename InT>
__global__ __launch_bounds__(256) void ln_kernel(const InT* __restrict__ x,
                                                 const float* __restrict__ g,
                                                 const float* __restrict__ b,
                                                 bf16* __restrict__ out, int D) {
    const int row = blockIdx.x;
    const InT* xr = x + (size_t)row * D;
    float s = 0.f, s2 = 0.f;
    for (int i = threadIdx.x; i < D; i += 256) {
        float v = toF(xr[i]);
        s += v; s2 += v * v;
    }
    __shared__ float ws[4], ws2[4];
    int lane = threadIdx.x & 63, wid = threadIdx.x >> 6;
    s = waveReduceSum(s); s2 = waveReduceSum(s2);
    if (lane == 0) { ws[wid] = s; ws2[wid] = s2; }
    __syncthreads();
    float ts = ws[0] + ws[1] + ws[2] + ws[3];
    float ts2 = ws2[0] + ws2[1] + ws2[2] + ws2[3];
    float mean = ts / D;
    float var = ts2 / D - mean * mean;
    float rstd = rsqrtf(var + 1e-5f);
    bf16* outr = out + (size_t)row * D;
    for (int i = threadIdx.x; i < D; i += 256) {
        float v = (toF(xr[i]) - mean) * rstd * g[i] + b[i];
        outr[i] = __float2bfloat16(v);
    }
}

// ---------------- MFMA GEMM: C = act(A @ BT^T + bias) [+ resid] ------------
// BM = 128 (4 waves 2x2 of 64x64) or 64 (4 waves 2x2 of 32x64). BN=128.
template <int BM, typename OutT, typename ResidT, bool RELU, bool HAS_RESID, bool BIAS3>
__global__ __launch_bounds__(256) void gemm_mfma(const bf16* __restrict__ A,
                                                 const bf16* __restrict__ BT,
                                                 const float* __restrict__ bias,
                                                 const float* __restrict__ biasK,
                                                 const float* __restrict__ biasV,
                                                 const ResidT* __restrict__ resid,
                                                 OutT* __restrict__ C,
                                                 int M, int N, int K) {
    constexpr int BK = 32;
    constexpr int MI = BM / 32;      // m-frags per wave (4 or 2)
    __shared__ bf16 As[BM][BK];
    __shared__ bf16 Bs[128][BK];
    const int tid = threadIdx.x, lane = tid & 63, wid = tid >> 6;
    const int m0 = blockIdx.y * BM, n0 = blockIdx.x * 128;
    const int wm = (BM == 128) ? (wid >> 1) * 64 : (wid & 1) * 32;
    const int wn = (BM == 128) ? (wid & 1) * 64 : (wid >> 1) * 64;

    f32x4 acc[MI][4] = {};

    const int srow = wid * 16 + (lane >> 2);
    const int scol = (lane & 3) * 8;
    const size_t aBase0 = (size_t)(m0 + srow) * K + scol;
    const size_t aBase1 = (size_t)(m0 + (BM == 128 ? 64 : 0) + srow) * K + scol;
    const size_t bBase0 = (size_t)(n0 + srow) * K + scol;
    const size_t bBase1 = (size_t)(n0 + 64 + srow) * K + scol;

    const int fr = lane & 15;
    const int fk = (lane >> 4) * 8;

    for (int k0 = 0; k0 < K; k0 += BK) {
        async16(A + aBase0 + k0, &As[wid * 16][0]);
        if (BM == 128)
            async16(A + aBase1 + k0, &As[(BM == 128 ? 64 : 0) + wid * 16][0]);
        async16(BT + bBase0 + k0, &Bs[wid * 16][0]);
        async16(BT + bBase1 + k0, &Bs[64 + wid * 16][0]);
        __syncthreads();

        bf16x8 aF[MI], bF[4];
        #pragma unroll
        for (int i = 0; i < MI; ++i)
            aF[i] = *(const bf16x8*)&As[wm + i * 16 + fr][fk];
        #pragma unroll
        for (int j = 0; j < 4; ++j)
            bF[j] = *(const bf16x8*)&Bs[wn + j * 16 + fr][fk];
        #pragma unroll
        for (int i = 0; i < MI; ++i)
            #pragma unroll
            for (int j = 0; j < 4; ++j)
                acc[i][j] = __builtin_amdgcn_mfma_f32_16x16x32_bf16(
                    aF[i], bF[j], acc[i][j], 0, 0, 0);
        __syncthreads();
    }

    const int col_l = lane & 15, row_l = (lane >> 4) * 4;
    #pragma unroll
    for (int j = 0; j < 4; ++j) {
        const int col = n0 + wn + j * 16 + col_l;
        float bvv;
        if (BIAS3) {
            const float* bp = (col < 1024) ? bias : ((col < 2048) ? biasK : biasV);
            bvv = bp[col & 1023];
        } else {
            bvv = bias[col];
        }
        #pragma unroll
        for (int i = 0; i < MI; ++i) {
            #pragma unroll
            for (int r = 0; r < 4; ++r) {
                const int row = m0 + wm + i * 16 + row_l + r;
                float v = acc[i][j][r] + bvv;
                if (RELU) v = fmaxf(v, 0.f);
                if (HAS_RESID) v += toF(resid[(size_t)row * N + col]);
                storeF(&C[(size_t)row * N + col], v);
            }
        }
    }
}

// ---------------- MFMA flash attention, S^T formulation --------------------
// grid (S/64, H, B), block 256 = 4 waves; wave w owns q-rows [w*16,w*16+16).
// qkv [M, LD=3072]: q col 0, k col 1024, v col 2048; head h: +h*64.
#if HAVE_MFMA_K16
__global__ __launch_bounds__(256) void attn_mfma(const bf16* __restrict__ qkv,
                                                 const int* __restrict__ mask,
                                                 bf16* __restrict__ outp,
                                                 int B, int S, int LD) {
    const int q0 = blockIdx.x * 64;
    const int h = blockIdx.y, b = blockIdx.z;
    const int Do = 1024;
    const int tid = threadIdx.x, lane = tid & 63, wid = tid >> 6;
    const int n = lane & 15, kg = lane >> 4;

    __shared__ bf16 Ks[64][66];     // K tile [j][d], 132B rows
    __shared__ bf16 Vt[64][68];     // V^T tile [d][j], 136B rows (34 dwords)
    __shared__ float Mskf[64];      // additive mask bias

    // Q B-frags, pre-scaled by 1/sqrt(64) = 2^-3 (exact)
    bf16x8 qf[2];
    {
        const bf16* qp = qkv + ((size_t)(b * S + q0 + wid * 16 + n)) * LD + h * 64 + kg * 8;
        union { uint4 u; bf16x8 v; unsigned short s[8]; } c[2];
        c[0].u = *(const uint4*)qp;
        c[1].u = *(const uint4*)(qp + 32);
        #pragma unroll
        for (int t = 0; t < 2; ++t) {
            #pragma unroll
            for (int i = 0; i < 8; ++i) {
                union { float f; unsigned int u; } d;
                d.u = ((unsigned int)c[t].s[i]) << 16;
                c[t].s[i] = bf16bits(d.f * 0.125f);
            }
            qf[t] = c[t].v;
        }
    }

    f32x4 acc_o[4] = {};
    float m = -1e30f, l = 0.f;

    const int sr = tid >> 2, sc = (tid & 3) * 16;   // K staging: row, d-chunk
    const int jp = tid & 31, dg = (tid >> 5) * 8;   // V staging: j-pair, d-chunk
    const bf16* kbase = qkv + (size_t)(b * S) * LD + 1024 + h * 64;
    const bf16* vbase = qkv + (size_t)(b * S) * LD + 2048 + h * 64;

    for (int j0 = 0; j0 < S; j0 += 64) {
        __syncthreads();
        {
            const bf16* kp = kbase + (size_t)(j0 + sr) * LD + sc;
            uint4 ka = *(const uint4*)kp;
            uint4 kc = *(const uint4*)(kp + 8);
            uint* kd = (uint*)((char*)&Ks[0][0] + sr * 132 + sc * 2);
            kd[0] = ka.x; kd[1] = ka.y; kd[2] = ka.z; kd[3] = ka.w;
            kd[4] = kc.x; kd[5] = kc.y; kd[6] = kc.z; kd[7] = kc.w;

            // V: rows 2jp, 2jp+1; d-range dg..dg+7; pair-packed b32 into Vt.
            // jp = tid&31 => within each 32-lane group banks 2i+jp are distinct.
            const bf16* vp = vbase + (size_t)(j0 + 2 * jp) * LD + dg;
            union { uint4 u; unsigned short s[8]; } va, vc;
            va.u = *(const uint4*)vp;
            vc.u = *(const uint4*)(vp + LD);
            #pragma unroll
            for (int i = 0; i < 8; ++i) {
                unsigned int pk = (unsigned int)va.s[i] | ((unsigned int)vc.s[i] << 16);
                *(unsigned int*)((char*)&Vt[0][0] + (size_t)(dg + i) * 136 + jp * 4) = pk;
            }
            if (tid < 64) Mskf[tid] = (mask[b * S + j0 + tid] == 0) ? -1e9f : 0.f;
        }
        __syncthreads();

        // ---- S^T = K @ Q^T : lane holds S^T[j=jt*16+kg*4+r][q=n] ----
        f32x4 st[4] = {};
        #pragma unroll
        for (int ks = 0; ks < 2; ++ks) {
            #pragma unroll
            for (int jt = 0; jt < 4; ++jt) {
                union { uint u[4]; bf16x8 v; } kf;
                const uint* bp = (const uint*)((const char*)&Ks[0][0]
                                 + (size_t)(jt * 16 + n) * 132 + ks * 64 + kg * 16);
                kf.u[0] = bp[0]; kf.u[1] = bp[1]; kf.u[2] = bp[2]; kf.u[3] = bp[3];
                st[jt] = __builtin_amdgcn_mfma_f32_16x16x32_bf16(kf.v, qf[ks], st[jt], 0, 0, 0);
            }
        }

        // ---- online softmax (per-lane state, 2 shfls per reduction) ----
        float mx = m;
        #pragma unroll
        for (int jt = 0; jt < 4; ++jt) {
            f32x4 mb = *(const f32x4*)&Mskf[jt * 16 + kg * 4];
            #pragma unroll
            for (int r = 0; r < 4; ++r) {
                st[jt][r] += mb[r];
                mx = fmaxf(mx, st[jt][r]);
            }
        }
        mx = fmaxf(mx, __shfl_xor(mx, 16, 64));
        mx = fmaxf(mx, __shfl_xor(mx, 32, 64));
        float alpha = __expf(m - mx);
        m = mx;
        float ls = 0.f;
        bf16x4v pf[4];
        #pragma unroll
        for (int jt = 0; jt < 4; ++jt) {
            union { unsigned short s[4]; bf16x4v v; } pk;
            #pragma unroll
            for (int r = 0; r < 4; ++r) {
                float p = __expf(st[jt][r] - m);
                ls += p;
                pk.s[r] = bf16bits(p);
            }
            pf[jt] = pk.v;
        }
        ls += __shfl_xor(ls, 16, 64);
        ls += __shfl_xor(ls, 32, 64);
        l = l * alpha + ls;
        #pragma unroll
        for (int dt = 0; dt < 4; ++dt)
            #pragma unroll
            for (int r = 0; r < 4; ++r) acc_o[dt][r] *= alpha;

        // ---- O^T += V^T @ P^T  (A = V^T from Vt, B = P^T from registers) ----
        #pragma unroll
        for (int jt = 0; jt < 4; ++jt) {
            #pragma unroll
            for (int dt = 0; dt < 4; ++dt) {
                union { uint u[2]; bf16x4v v; } vf;
                const uint* vpp = (const uint*)((const char*)&Vt[0][0]
                                  + (size_t)(dt * 16 + n) * 136 + jt * 32 + kg * 8);
                vf.u[0] = vpp[0]; vf.u[1] = vpp[1];
                acc_o[dt] = __builtin_amdgcn_mfma_f32_16x16x16bf16_1k(
                    vf.v, pf[jt], acc_o[dt], 0, 0, 0);
            }
        }
    }

    // ---- epilogue ----
    float inv = (l > 0.f) ? (1.f / l) : 0.f;
    bf16* op = outp + ((size_t)(b * S + q0 + wid * 16 + n)) * Do + h * 64;
    #pragma unroll
    for (int dt = 0; dt < 4; ++dt) {
        union { unsigned short s[4]; uint2 u; } w;
        #pragma unroll
        for (int r = 0; r < 4; ++r) w.s[r] = bf16bits(acc_o[dt][r] * inv);
        *(uint2*)(op + dt * 16 + kg * 4) = w.u;
    }
}
#else
// Fallback (round-5 structure, strided qkv).
__global__ __launch_bounds__(256) void attn_mfma(const bf16* __restrict__ qkv,
                                                 const int* __restrict__ mask,
                                                 bf16* __restrict__ outp,
                                                 int B, int S, int LD) {
    const int q0 = blockIdx.x * 64;
    const int h = blockIdx.y, b = blockIdx.z;
    const int Do = 1024;
    const int tid = threadIdx.x, lane = tid & 63, wid = tid >> 6;
    const int n = lane & 15, kg = lane >> 4;

    __shared__ bf16 Ks[64][66];
    __shared__ bf16 Vt[64][66];
    __shared__ bf16 Plds[4][16][66];
    __shared__ int  Msk[64];

    bf16x8 qf[2];
    {
        const bf16* qp = qkv + ((size_t)(b * S + q0 + wid * 16 + n)) * LD + h * 64 + kg * 8;
        union { uint4 u; bf16x8 v; } c0, c1;
        c0.u = *(const uint4*)qp;
        c1.u = *(const uint4*)(qp + 32);
        qf[0] = c0.v; qf[1] = c1.v;
    }

    f32x4 acc_o[4] = {};
    float m_r[4] = {-1e30f, -1e30f, -1e30f, -1e30f};
    float l_r[4] = {0.f, 0.f, 0.f, 0.f};

    const int sr = tid >> 2;
    const int sc = (tid & 3) * 16;
    const bf16* kbase = qkv + (size_t)(b * S) * LD + 1024 + h * 64;
    const bf16* vbase = qkv + (size_t)(b * S) * LD + 2048 + h * 64;

    for (int j0 = 0; j0 < S; j0 += 64) {
        __syncthreads();
        {
            const bf16* kp = kbase + (size_t)(j0 + sr) * LD + sc;
            uint4 ka = *(const uint4*)kp;
            uint4 kbv = *(const uint4*)(kp + 8);
            uint* kd = (uint*)((char*)&Ks[0][0] + sr * 132 + sc * 2);
            kd[0] = ka.x; kd[1] = ka.y; kd[2] = ka.z; kd[3] = ka.w;
            kd[4] = kbv.x; kd[5] = kbv.y; kd[6] = kbv.z; kd[7] = kbv.w;

            const bf16* vp = vbase + (size_t)(j0 + sr) * LD + sc;
            union { uint4 u[2]; unsigned short s[16]; } vv;
            vv.u[0] = *(const uint4*)vp;
            vv.u[1] = *(const uint4*)(vp + 8);
            #pragma unroll
            for (int i = 0; i < 16; ++i)
                *((unsigned short*)((char*)&Vt[0][0] + (size_t)(sc + i) * 132 + sr * 2)) = vv.s[i];

            if (tid < 64) Msk[tid] = mask[b * S + j0 + tid];
        }
        __syncthreads();

        f32x4 st[4] = {};
        #pragma unroll
        for (int ks = 0; ks < 2; ++ks) {
            #pragma unroll
            for (int jt = 0; jt < 4; ++jt) {
                union { uint u[4]; bf16x8 v; } bf;
                const uint* bp = (const uint*)((const char*)&Ks[0][0]
                                 + (size_t)(jt * 16 + n) * 132 + ks * 64 + kg * 16);
                bf.u[0] = bp[0]; bf.u[1] = bp[1]; bf.u[2] = bp[2]; bf.u[3] = bp[3];
                st[jt] = __builtin_amdgcn_mfma_f32_16x16x32_bf16(qf[ks], bf.v, st[jt], 0, 0, 0);
            }
        }

        int mk[4];
        #pragma unroll
        for (int jt = 0; jt < 4; ++jt) mk[jt] = Msk[jt * 16 + n];

        #pragma unroll
        for (int r = 0; r < 4; ++r) {
            float mx = -1e30f;
            #pragma unroll
            for (int jt = 0; jt < 4; ++jt) {
                float s = st[jt][r] * 0.125f;
                if (mk[jt] == 0) s = -1e9f;
                st[jt][r] = s;
                mx = fmaxf(mx, s);
            }
            #pragma unroll
            for (int o = 1; o < 16; o <<= 1) mx = fmaxf(mx, __shfl_xor(mx, o, 64));
            float newm = fmaxf(m_r[r], mx);
            float alpha = __expf(m_r[r] - newm);
            m_r[r] = newm;
            float ls = 0.f;
            #pragma unroll
            for (int jt = 0; jt < 4; ++jt) {
                float p = __expf(st[jt][r] - newm);
                ls += p;
                Plds[wid][kg * 4 + r][jt * 16 + n] = __float2bfloat16(p);
            }
            #pragma unroll
            for (int o = 1; o < 16; o <<= 1) ls += __shfl_xor(ls, o, 64);
            l_r[r] = l_r[r] * alpha + ls;
            #pragma unroll
            for (int dt = 0; dt < 4; ++dt) acc_o[dt][r] *= alpha;
        }

        __asm__ volatile("s_waitcnt lgkmcnt(0)" ::: "memory");

        #pragma unroll
        for (int ks = 0; ks < 2; ++ks) {
            union { uint u[4]; bf16x8 v; } af;
            const uint* ap = (const uint*)((const char*)&Plds[wid][0][0]
                             + (size_t)n * 132 + ks * 64 + kg * 16);
            af.u[0] = ap[0]; af.u[1] = ap[1]; af.u[2] = ap[2]; af.u[3] = ap[3];
            #pragma unroll
            for (int dt = 0; dt < 4; ++dt) {
                union { uint u[4]; bf16x8 v; } bf;
                const uint* bp = (const uint*)((const char*)&Vt[0][0]
                                 + (size_t)(dt * 16 + n) * 132 + ks * 64 + kg * 16);
                bf.u[0] = bp[0]; bf.u[1] = bp[1]; bf.u[2] = bp[2]; bf.u[3] = bp[3];
                acc_o[dt] = __builtin_amdgcn_mfma_f32_16x16x32_bf16(af.v, bf.v, acc_o[dt], 0, 0, 0);
            }
        }
    }

    #pragma unroll
    for (int r = 0; r < 4; ++r) {
        float inv = (l_r[r] > 0.f) ? (1.f / l_r[r]) : 0.f;
        bf16* op = outp + ((size_t)(b * S + q0 + wid * 16 + kg * 4 + r)) * Do + h * 64 + n;
        #pragma unroll
        for (int dt = 0; dt < 4; ++dt)
            op[dt * 16] = __float2bfloat16(acc_o[dt][r] * inv);
    }
}
#endif

extern "C" void kernel_launch(void* const* d_in, const int* in_sizes, int n_in,
                              void* d_out, int out_size, void* d_ws, size_t ws_size,
                              hipStream_t stream) {
    const int B = 2, S = 2048, D = 1024, H = 16, F = 4096;
    const int M = B * S;  // 4096

    const float* x   = (const float*)d_in[0];
    const int*   mask= (const int*)  d_in[1];
    const float* wq  = (const float*)d_in[2];
    const float* bq  = (const float*)d_in[3];
    const float* wk  = (const float*)d_in[4];
    const float* bk  = (const float*)d_in[5];
    const float* wv  = (const float*)d_in[6];
    const float* bv  = (const float*)d_in[7];
    const float* wo  = (const float*)d_in[8];
    const float* bo  = (const float*)d_in[9];
    const float* g1  = (const float*)d_in[10];
    const float* be1 = (const float*)d_in[11];
    const float* g2  = (const float*)d_in[12];
    const float* be2 = (const float*)d_in[13];
    const float* w1  = (const float*)d_in[14];
    const float* bf1 = (const float*)d_in[15];
    const float* w2  = (const float*)d_in[16];
    const float* bf2 = (const float*)d_in[17];
    float* out = (float*)d_out;

    char* ws = (char*)d_ws;
    const size_t MB = 1024 * 1024;
    bf16* wqkvT = (bf16*)(ws + 0 * MB);            // [3072,1024]
    bf16* woT   = (bf16*)(ws + 6 * MB);
    bf16* w1T   = (bf16*)(ws + 8 * MB);
    bf16* w2T   = (bf16*)(ws + 16 * MB);
    bf16* xn    = (bf16*)(ws + 24 * MB);
    bf16* qkv   = (bf16*)(ws + 32 * MB);           // [4096,3072]
    bf16* att   = xn;                              // reuse
    // x2 (fp32 residual carrier) lives in d_out.

    const bool fullM = (ws_size >= 64 * MB);

    // weight transposes
    transpose_cast<<<dim3(D / 32, D / 32), 256, 0, stream>>>(wq, wqkvT, D, D);
    transpose_cast<<<dim3(D / 32, D / 32), 256, 0, stream>>>(wk, wqkvT + (size_t)1024 * 1024, D, D);
    transpose_cast<<<dim3(D / 32, D / 32), 256, 0, stream>>>(wv, wqkvT + (size_t)2048 * 1024, D, D);
    transpose_cast<<<dim3(D / 32, D / 32), 256, 0, stream>>>(wo, woT, D, D);
    transpose_cast<<<dim3(F / 32, D / 32), 256, 0, stream>>>(w1, w1T, D, F);
    transpose_cast<<<dim3(D / 32, F / 32), 256, 0, stream>>>(w2, w2T, F, D);

    // LN1
    ln_kernel<float><<<M, 256, 0, stream>>>(x, g1, be1, xn, D);

    // fused QKV GEMM
    gemm_mfma<128, bf16, float, false, false, true><<<dim3(3072 / 128, M / 128), 256, 0, stream>>>(
        xn, wqkvT, bq, bk, bv, (const float*)nullptr, qkv, M, 3072, D);

    // attention
    attn_mfma<<<dim3(S / 64, H, B), 256, 0, stream>>>(qkv, mask, att, B, S, 3072);

    // out-proj + residual(x fp32) -> x2 = d_out (fp32); BM=64 -> 512 blocks
    gemm_mfma<64, float, float, false, true, false><<<dim3(D / 128, M / 64), 256, 0, stream>>>(
        att, woT, bo, nullptr, nullptr, x, out, M, D, D);

    if (fullM) {
        bf16* hid = (bf16*)(ws + 24 * MB);   // [4096,4096] at [24,56)
        bf16* xn2 = (bf16*)(ws + 56 * MB);   // [4096,1024] at [56,64)
        // LN2: d_out(fp32) -> xn2
        ln_kernel<float><<<M, 256, 0, stream>>>(out, g2, be2, xn2, D);
        // FFN up + ReLU (full M)
        gemm_mfma<128, bf16, float, true, false, false><<<dim3(F / 128, M / 128), 256, 0, stream>>>(
            xn2, w1T, bf1, nullptr, nullptr, (const float*)nullptr, hid, M, F, D);
        // FFN down + residual(d_out) -> d_out; BM=64 -> 512 blocks
        gemm_mfma<64, float, float, false, true, false><<<dim3(D / 128, M / 64), 256, 0, stream>>>(
            hid, w2T, bf2, nullptr, nullptr, out, out, M, D, F);
    } else {
        bf16* xn2 = (bf16*)(ws + 32 * MB);   // q-section reuse
        bf16* hid = (bf16*)(ws + 40 * MB);   // k+v sections, [2048,4096]
        const int CH = 2048;
        ln_kernel<float><<<M, 256, 0, stream>>>(out, g2, be2, xn2, D);
        for (int c = 0; c < M / CH; ++c) {
            const size_t roff = (size_t)c * CH;
            gemm_mfma<128, bf16, float, true, false, false><<<dim3(F / 128, CH / 128), 256, 0, stream>>>(
                xn2 + roff * D, w1T, bf1, nullptr, nullptr, (const float*)nullptr, hid, CH, F, D);
            gemm_mfma<64, float, float, false, true, false><<<dim3(D / 128, CH / 64), 256, 0, stream>>>(
                hid, w2T, bf2, nullptr, nullptr, out + roff * D, out + roff * D, CH, D, F);
        }
    }
}

// Round 8
// 429.925 us; speedup vs baseline: 6.3117x; 1.0313x over previous
//
#include <hip/hip_runtime.h>
#include <hip/hip_bf16.h>

// Transformer block: LN1 -> QKV -> MHA(16 heads, hd=64) -> out-proj + resid
//                    -> LN2 -> FFN(4x, ReLU) + resid
// B=2, S=2048, D=1024, H=16, hd=64, F=4096. M = B*S = 4096.
// fp32 buffers in/out; bf16 intermediates (fp32 accumulation).
//
// Round 8:
//  (a) attention TQ=128 (wave owns 32 q-rows as two 16-q groups). K-frags and
//      V-frags are read from LDS ONCE per tile and shared across both groups
//      -> LDS reads, staging VALU, and barriers per unit work are halved.
//      Grid 512 blocks = 2/CU.
//  (b) 6 weight-transpose launches fused into one kernel (12288 tiles).
//  GEMM pipeline unchanged from round 7 (BM=64 for N=1024 GEMMs, fused QKV,
//  x2 residual carrier in d_out fp32, full-M FFN when ws >= 64MB).

using bf16 = __hip_bfloat16;
typedef short bf16x8 __attribute__((ext_vector_type(8)));
typedef short bf16x4v __attribute__((ext_vector_type(4)));
typedef float f32x4 __attribute__((ext_vector_type(4)));

#if defined(__has_builtin)
#  if __has_builtin(__builtin_amdgcn_mfma_f32_16x16x16bf16_1k)
#    define HAVE_MFMA_K16 1
#  endif
#endif

__device__ __forceinline__ float toF(float v) { return v; }
__device__ __forceinline__ float toF(bf16 v) { return __bfloat162float(v); }
__device__ __forceinline__ void storeF(float* p, float v) { *p = v; }
__device__ __forceinline__ void storeF(bf16* p, float v) { *p = __float2bfloat16(v); }

__device__ __forceinline__ float waveReduceSum(float v) {
    #pragma unroll
    for (int o = 32; o > 0; o >>= 1) v += __shfl_down(v, o, 64);
    return v;
}

__device__ __forceinline__ void async16(const bf16* g, bf16* l) {
    __builtin_amdgcn_global_load_lds(
        (const __attribute__((address_space(1))) unsigned int*)g,
        (__attribute__((address_space(3))) unsigned int*)l,
        16, 0, 0);
}

__device__ __forceinline__ unsigned short bf16bits(float x) {
    union { bf16 h; unsigned short u; } e; e.h = __float2bfloat16(x);
    return e.u;
}

// ---------------- fused weight transpose + cast (all 6 weights) ------------
// tiles: [0,4096) wq/wk/wv/wo (1024 each), [4096,8192) w1, [8192,12288) w2.
__global__ __launch_bounds__(256) void transpose_all(
        const float* __restrict__ wq, const float* __restrict__ wk,
        const float* __restrict__ wv, const float* __restrict__ wo,
        const float* __restrict__ w1, const float* __restrict__ w2,
        bf16* __restrict__ wqkvT, bf16* __restrict__ woT,
        bf16* __restrict__ w1T, bf16* __restrict__ w2T) {
    __shared__ float t[32][33];
    const int tI = blockIdx.x;
    const float* in; bf16* outT; int R, C, tl;
    if (tI < 4096) {
        const int seg = tI >> 10; tl = tI & 1023; R = 1024; C = 1024;
        in = (seg == 0) ? wq : (seg == 1) ? wk : (seg == 2) ? wv : wo;
        outT = (seg == 3) ? woT : wqkvT + (size_t)seg * 1024 * 1024;
    } else if (tI < 8192) {
        tl = tI - 4096; in = w1; outT = w1T; R = 1024; C = 4096;
    } else {
        tl = tI - 8192; in = w2; outT = w2T; R = 4096; C = 1024;
    }
    const int tc = C >> 5;
    const int c0 = (tl % tc) * 32, r0 = (tl / tc) * 32;
    const int lx = threadIdx.x & 31, ly = threadIdx.x >> 5;
    #pragma unroll
    for (int i = 0; i < 32; i += 8)
        t[ly + i][lx] = in[(size_t)(r0 + ly + i) * C + c0 + lx];
    __syncthreads();
    #pragma unroll
    for (int i = 0; i < 32; i += 8)
        outT[(size_t)(c0 + ly + i) * R + r0 + lx] = __float2bfloat16(t[lx][ly + i]);
}

// ---------------- LayerNorm: InT x -> bf16 out ----------------
template <typename InT>
__global__ __launch_bounds__(256) void ln_kernel(const InT* __restrict__ x,
                                                 const float* __restrict__ g,
                                                 const float* __restrict__ b,
                                                 bf16* __restrict__ out, int D) {
    const int row = blockIdx.x;
    const InT* xr = x + (size_t)row * D;
    float s = 0.f, s2 = 0.f;
    for (int i = threadIdx.x; i < D; i += 256) {
        float v = toF(xr[i]);
        s += v; s2 += v * v;
    }
    __shared__ float ws[4], ws2[4];
    int lane = threadIdx.x & 63, wid = threadIdx.x >> 6;
    s = waveReduceSum(s); s2 = waveReduceSum(s2);
    if (lane == 0) { ws[wid] = s; ws2[wid] = s2; }
    __syncthreads();
    float ts = ws[0] + ws[1] + ws[2] + ws[3];
    float ts2 = ws2[0] + ws2[1] + ws2[2] + ws2[3];
    float mean = ts / D;
    float var = ts2 / D - mean * mean;
    float rstd = rsqrtf(var + 1e-5f);
    bf16* outr = out + (size_t)row * D;
    for (int i = threadIdx.x; i < D; i += 256) {
        float v = (toF(xr[i]) - mean) * rstd * g[i] + b[i];
        outr[i] = __float2bfloat16(v);
    }
}

// ---------------- MFMA GEMM: C = act(A @ BT^T + bias) [+ resid] ------------
// BM = 128 (4 waves 2x2 of 64x64) or 64 (4 waves 2x2 of 32x64). BN=128.
template <int BM, typename OutT, typename ResidT, bool RELU, bool HAS_RESID, bool BIAS3>
__global__ __launch_bounds__(256) void gemm_mfma(const bf16* __restrict__ A,
                                                 const bf16* __restrict__ BT,
                                                 const float* __restrict__ bias,
                                                 const float* __restrict__ biasK,
                                                 const float* __restrict__ biasV,
                                                 const ResidT* __restrict__ resid,
                                                 OutT* __restrict__ C,
                                                 int M, int N, int K) {
    constexpr int BK = 32;
    constexpr int MI = BM / 32;      // m-frags per wave (4 or 2)
    __shared__ bf16 As[BM][BK];
    __shared__ bf16 Bs[128][BK];
    const int tid = threadIdx.x, lane = tid & 63, wid = tid >> 6;
    const int m0 = blockIdx.y * BM, n0 = blockIdx.x * 128;
    const int wm = (BM == 128) ? (wid >> 1) * 64 : (wid & 1) * 32;
    const int wn = (BM == 128) ? (wid & 1) * 64 : (wid >> 1) * 64;

    f32x4 acc[MI][4] = {};

    const int srow = wid * 16 + (lane >> 2);
    const int scol = (lane & 3) * 8;
    const size_t aBase0 = (size_t)(m0 + srow) * K + scol;
    const size_t aBase1 = (size_t)(m0 + (BM == 128 ? 64 : 0) + srow) * K + scol;
    const size_t bBase0 = (size_t)(n0 + srow) * K + scol;
    const size_t bBase1 = (size_t)(n0 + 64 + srow) * K + scol;

    const int fr = lane & 15;
    const int fk = (lane >> 4) * 8;

    for (int k0 = 0; k0 < K; k0 += BK) {
        async16(A + aBase0 + k0, &As[wid * 16][0]);
        if (BM == 128)
            async16(A + aBase1 + k0, &As[(BM == 128 ? 64 : 0) + wid * 16][0]);
        async16(BT + bBase0 + k0, &Bs[wid * 16][0]);
        async16(BT + bBase1 + k0, &Bs[64 + wid * 16][0]);
        __syncthreads();

        bf16x8 aF[MI], bF[4];
        #pragma unroll
        for (int i = 0; i < MI; ++i)
            aF[i] = *(const bf16x8*)&As[wm + i * 16 + fr][fk];
        #pragma unroll
        for (int j = 0; j < 4; ++j)
            bF[j] = *(const bf16x8*)&Bs[wn + j * 16 + fr][fk];
        #pragma unroll
        for (int i = 0; i < MI; ++i)
            #pragma unroll
            for (int j = 0; j < 4; ++j)
                acc[i][j] = __builtin_amdgcn_mfma_f32_16x16x32_bf16(
                    aF[i], bF[j], acc[i][j], 0, 0, 0);
        __syncthreads();
    }

    const int col_l = lane & 15, row_l = (lane >> 4) * 4;
    #pragma unroll
    for (int j = 0; j < 4; ++j) {
        const int col = n0 + wn + j * 16 + col_l;
        float bvv;
        if (BIAS3) {
            const float* bp = (col < 1024) ? bias : ((col < 2048) ? biasK : biasV);
            bvv = bp[col & 1023];
        } else {
            bvv = bias[col];
        }
        #pragma unroll
        for (int i = 0; i < MI; ++i) {
            #pragma unroll
            for (int r = 0; r < 4; ++r) {
                const int row = m0 + wm + i * 16 + row_l + r;
                float v = acc[i][j][r] + bvv;
                if (RELU) v = fmaxf(v, 0.f);
                if (HAS_RESID) v += toF(resid[(size_t)row * N + col]);
                storeF(&C[(size_t)row * N + col], v);
            }
        }
    }
}

// ---------------- MFMA flash attention, S^T formulation, TQ=128 ------------
// grid (S/128, H, B), block 256 = 4 waves; wave w owns q-rows
// [w*32, w*32+32) as two 16-q groups u=0,1. K/V fragments read once per tile
// and shared across both groups.
#if HAVE_MFMA_K16
__global__ __launch_bounds__(256) void attn_mfma(const bf16* __restrict__ qkv,
                                                 const int* __restrict__ mask,
                                                 bf16* __restrict__ outp,
                                                 int B, int S, int LD) {
    const int q0 = blockIdx.x * 128;
    const int h = blockIdx.y, b = blockIdx.z;
    const int Do = 1024;
    const int tid = threadIdx.x, lane = tid & 63, wid = tid >> 6;
    const int n = lane & 15, kg = lane >> 4;

    __shared__ bf16 Ks[64][66];     // K tile [j][d], 132B rows
    __shared__ bf16 Vt[64][68];     // V^T tile [d][j], 136B rows
    __shared__ float Mskf[64];      // additive mask bias

    // Q B-frags for both q-groups, pre-scaled by 1/sqrt(64) = 2^-3 (exact)
    bf16x8 qf[2][2];
    #pragma unroll
    for (int u = 0; u < 2; ++u) {
        const bf16* qp = qkv + ((size_t)(b * S + q0 + wid * 32 + u * 16 + n)) * LD + h * 64 + kg * 8;
        union { uint4 uu; bf16x8 v; unsigned short s[8]; } c[2];
        c[0].uu = *(const uint4*)qp;
        c[1].uu = *(const uint4*)(qp + 32);
        #pragma unroll
        for (int t = 0; t < 2; ++t) {
            #pragma unroll
            for (int i = 0; i < 8; ++i) {
                union { float f; unsigned int u2; } d;
                d.u2 = ((unsigned int)c[t].s[i]) << 16;
                c[t].s[i] = bf16bits(d.f * 0.125f);
            }
            qf[u][t] = c[t].v;
        }
    }

    f32x4 acc[2][4] = {};           // O^T per group
    float m[2] = {-1e30f, -1e30f}, l[2] = {0.f, 0.f};

    const int sr = tid >> 2, sc = (tid & 3) * 16;   // K staging: row, d-chunk
    const int jp = tid & 31, dg = (tid >> 5) * 8;   // V staging: j-pair, d-chunk
    const bf16* kbase = qkv + (size_t)(b * S) * LD + 1024 + h * 64;
    const bf16* vbase = qkv + (size_t)(b * S) * LD + 2048 + h * 64;

    for (int j0 = 0; j0 < S; j0 += 64) {
        __syncthreads();
        {
            const bf16* kp = kbase + (size_t)(j0 + sr) * LD + sc;
            uint4 ka = *(const uint4*)kp;
            uint4 kc = *(const uint4*)(kp + 8);
            uint* kd = (uint*)((char*)&Ks[0][0] + sr * 132 + sc * 2);
            kd[0] = ka.x; kd[1] = ka.y; kd[2] = ka.z; kd[3] = ka.w;
            kd[4] = kc.x; kd[5] = kc.y; kd[6] = kc.z; kd[7] = kc.w;

            const bf16* vp = vbase + (size_t)(j0 + 2 * jp) * LD + dg;
            union { uint4 u; unsigned short s[8]; } va, vc;
            va.u = *(const uint4*)vp;
            vc.u = *(const uint4*)(vp + LD);
            #pragma unroll
            for (int i = 0; i < 8; ++i) {
                unsigned int pk = (unsigned int)va.s[i] | ((unsigned int)vc.s[i] << 16);
                *(unsigned int*)((char*)&Vt[0][0] + (size_t)(dg + i) * 136 + jp * 4) = pk;
            }
            if (tid < 64) Mskf[tid] = (mask[b * S + j0 + tid] == 0) ? -1e9f : 0.f;
        }
        __syncthreads();

        // ---- S^T = K @ Q^T for both groups; K-frags read once ----
        f32x4 st[2][4] = {};
        #pragma unroll
        for (int ks = 0; ks < 2; ++ks) {
            #pragma unroll
            for (int jt = 0; jt < 4; ++jt) {
                union { uint u[4]; bf16x8 v; } kf;
                const uint* bp = (const uint*)((const char*)&Ks[0][0]
                                 + (size_t)(jt * 16 + n) * 132 + ks * 64 + kg * 16);
                kf.u[0] = bp[0]; kf.u[1] = bp[1]; kf.u[2] = bp[2]; kf.u[3] = bp[3];
                st[0][jt] = __builtin_amdgcn_mfma_f32_16x16x32_bf16(kf.v, qf[0][ks], st[0][jt], 0, 0, 0);
                st[1][jt] = __builtin_amdgcn_mfma_f32_16x16x32_bf16(kf.v, qf[1][ks], st[1][jt], 0, 0, 0);
            }
        }

        // ---- online softmax per group ----
        bf16x4v pf[2][4];
        #pragma unroll
        for (int u = 0; u < 2; ++u) {
            float mx = m[u];
            #pragma unroll
            for (int jt = 0; jt < 4; ++jt) {
                f32x4 mb = *(const f32x4*)&Mskf[jt * 16 + kg * 4];
                #pragma unroll
                for (int r = 0; r < 4; ++r) {
                    st[u][jt][r] += mb[r];
                    mx = fmaxf(mx, st[u][jt][r]);
                }
            }
            mx = fmaxf(mx, __shfl_xor(mx, 16, 64));
            mx = fmaxf(mx, __shfl_xor(mx, 32, 64));
            float alpha = __expf(m[u] - mx);
            m[u] = mx;
            float ls = 0.f;
            #pragma unroll
            for (int jt = 0; jt < 4; ++jt) {
                union { unsigned short s[4]; bf16x4v v; } pk;
                #pragma unroll
                for (int r = 0; r < 4; ++r) {
                    float p = __expf(st[u][jt][r] - mx);
                    ls += p;
                    pk.s[r] = bf16bits(p);
                }
                pf[u][jt] = pk.v;
            }
            ls += __shfl_xor(ls, 16, 64);
            ls += __shfl_xor(ls, 32, 64);
            l[u] = l[u] * alpha + ls;
            #pragma unroll
            for (int dt = 0; dt < 4; ++dt)
                #pragma unroll
                for (int r = 0; r < 4; ++r) acc[u][dt][r] *= alpha;
        }

        // ---- O^T += V^T @ P^T; V-frags read once, applied to both groups ----
        #pragma unroll
        for (int jt = 0; jt < 4; ++jt) {
            #pragma unroll
            for (int dt = 0; dt < 4; ++dt) {
                union { uint u[2]; bf16x4v v; } vf;
                const uint* vpp = (const uint*)((const char*)&Vt[0][0]
                                  + (size_t)(dt * 16 + n) * 136 + jt * 32 + kg * 8);
                vf.u[0] = vpp[0]; vf.u[1] = vpp[1];
                acc[0][dt] = __builtin_amdgcn_mfma_f32_16x16x16bf16_1k(vf.v, pf[0][jt], acc[0][dt], 0, 0, 0);
                acc[1][dt] = __builtin_amdgcn_mfma_f32_16x16x16bf16_1k(vf.v, pf[1][jt], acc[1][dt], 0, 0, 0);
            }
        }
    }

    // ---- epilogue ----
    #pragma unroll
    for (int u = 0; u < 2; ++u) {
        float inv = (l[u] > 0.f) ? (1.f / l[u]) : 0.f;
        bf16* op = outp + ((size_t)(b * S + q0 + wid * 32 + u * 16 + n)) * Do + h * 64;
        #pragma unroll
        for (int dt = 0; dt < 4; ++dt) {
            union { unsigned short s[4]; uint2 u2; } w;
            #pragma unroll
            for (int r = 0; r < 4; ++r) w.s[r] = bf16bits(acc[u][dt][r] * inv);
            *(uint2*)(op + dt * 16 + kg * 4) = w.u2;
        }
    }
}
#else
// Fallback (round-5 structure); handles 128 q-rows as two sequential halves.
__global__ __launch_bounds__(256) void attn_mfma(const bf16* __restrict__ qkv,
                                                 const int* __restrict__ mask,
                                                 bf16* __restrict__ outp,
                                                 int B, int S, int LD) {
    const int h = blockIdx.y, b = blockIdx.z;
    const int Do = 1024;
    const int tid = threadIdx.x, lane = tid & 63, wid = tid >> 6;
    const int n = lane & 15, kg = lane >> 4;

    __shared__ bf16 Ks[64][66];
    __shared__ bf16 Vt[64][66];
    __shared__ bf16 Plds[4][16][66];
    __shared__ int  Msk[64];

    for (int half = 0; half < 2; ++half) {
        const int q0 = blockIdx.x * 128 + half * 64;
        __syncthreads();

        bf16x8 qf[2];
        {
            const bf16* qp = qkv + ((size_t)(b * S + q0 + wid * 16 + n)) * LD + h * 64 + kg * 8;
            union { uint4 u; bf16x8 v; } c0, c1;
            c0.u = *(const uint4*)qp;
            c1.u = *(const uint4*)(qp + 32);
            qf[0] = c0.v; qf[1] = c1.v;
        }

        f32x4 acc_o[4] = {};
        float m_r[4] = {-1e30f, -1e30f, -1e30f, -1e30f};
        float l_r[4] = {0.f, 0.f, 0.f, 0.f};

        const int sr = tid >> 2;
        const int sc = (tid & 3) * 16;
        const bf16* kbase = qkv + (size_t)(b * S) * LD + 1024 + h * 64;
        const bf16* vbase = qkv + (size_t)(b * S) * LD + 2048 + h * 64;

        for (int j0 = 0; j0 < S; j0 += 64) {
            __syncthreads();
            {
                const bf16* kp = kbase + (size_t)(j0 + sr) * LD + sc;
                uint4 ka = *(const uint4*)kp;
                uint4 kbv = *(const uint4*)(kp + 8);
                uint* kd = (uint*)((char*)&Ks[0][0] + sr * 132 + sc * 2);
                kd[0] = ka.x; kd[1] = ka.y; kd[2] = ka.z; kd[3] = ka.w;
                kd[4] = kbv.x; kd[5] = kbv.y; kd[6] = kbv.z; kd[7] = kbv.w;

                const bf16* vp = vbase + (size_t)(j0 + sr) * LD + sc;
                union { uint4 u[2]; unsigned short s[16]; } vv;
                vv.u[0] = *(const uint4*)vp;
                vv.u[1] = *(const uint4*)(vp + 8);
                #pragma unroll
                for (int i = 0; i < 16; ++i)
                    *((unsigned short*)((char*)&Vt[0][0] + (size_t)(sc + i) * 132 + sr * 2)) = vv.s[i];

                if (tid < 64) Msk[tid] = mask[b * S + j0 + tid];
            }
            __syncthreads();

            f32x4 st[4] = {};
            #pragma unroll
            for (int ks = 0; ks < 2; ++ks) {
                #pragma unroll
                for (int jt = 0; jt < 4; ++jt) {
                    union { uint u[4]; bf16x8 v; } bf;
                    const uint* bp = (const uint*)((const char*)&Ks[0][0]
                                     + (size_t)(jt * 16 + n) * 132 + ks * 64 + kg * 16);
                    bf.u[0] = bp[0]; bf.u[1] = bp[1]; bf.u[2] = bp[2]; bf.u[3] = bp[3];
                    st[jt] = __builtin_amdgcn_mfma_f32_16x16x32_bf16(qf[ks], bf.v, st[jt], 0, 0, 0);
                }
            }

            int mk[4];
            #pragma unroll
            for (int jt = 0; jt < 4; ++jt) mk[jt] = Msk[jt * 16 + n];

            #pragma unroll
            for (int r = 0; r < 4; ++r) {
                float mx = -1e30f;
                #pragma unroll
                for (int jt = 0; jt < 4; ++jt) {
                    float s = st[jt][r] * 0.125f;
                    if (mk[jt] == 0) s = -1e9f;
                    st[jt][r] = s;
                    mx = fmaxf(mx, s);
                }
                #pragma unroll
                for (int o = 1; o < 16; o <<= 1) mx = fmaxf(mx, __shfl_xor(mx, o, 64));
                float newm = fmaxf(m_r[r], mx);
                float alpha = __expf(m_r[r] - newm);
                m_r[r] = newm;
                float ls = 0.f;
                #pragma unroll
                for (int jt = 0; jt < 4; ++jt) {
                    float p = __expf(st[jt][r] - newm);
                    ls += p;
                    Plds[wid][kg * 4 + r][jt * 16 + n] = __float2bfloat16(p);
                }
                #pragma unroll
                for (int o = 1; o < 16; o <<= 1) ls += __shfl_xor(ls, o, 64);
                l_r[r] = l_r[r] * alpha + ls;
                #pragma unroll
                for (int dt = 0; dt < 4; ++dt) acc_o[dt][r] *= alpha;
            }

            __asm__ volatile("s_waitcnt lgkmcnt(0)" ::: "memory");

            #pragma unroll
            for (int ks = 0; ks < 2; ++ks) {
                union { uint u[4]; bf16x8 v; } af;
                const uint* ap = (const uint*)((const char*)&Plds[wid][0][0]
                                 + (size_t)n * 132 + ks * 64 + kg * 16);
                af.u[0] = ap[0]; af.u[1] = ap[1]; af.u[2] = ap[2]; af.u[3] = ap[3];
                #pragma unroll
                for (int dt = 0; dt < 4; ++dt) {
                    union { uint u[4]; bf16x8 v; } bf;
                    const uint* bp = (const uint*)((const char*)&Vt[0][0]
                                     + (size_t)(dt * 16 + n) * 132 + ks * 64 + kg * 16);
                    bf.u[0] = bp[0]; bf.u[1] = bp[1]; bf.u[2] = bp[2]; bf.u[3] = bp[3];
                    acc_o[dt] = __builtin_amdgcn_mfma_f32_16x16x32_bf16(af.v, bf.v, acc_o[dt], 0, 0, 0);
                }
            }
        }

        #pragma unroll
        for (int r = 0; r < 4; ++r) {
            float inv = (l_r[r] > 0.f) ? (1.f / l_r[r]) : 0.f;
            bf16* op = outp + ((size_t)(b * S + q0 + wid * 16 + kg * 4 + r)) * Do + h * 64 + n;
            #pragma unroll
            for (int dt = 0; dt < 4; ++dt)
                op[dt * 16] = __float2bfloat16(acc_o[dt][r] * inv);
        }
    }
}
#endif

extern "C" void kernel_launch(void* const* d_in, const int* in_sizes, int n_in,
                              void* d_out, int out_size, void* d_ws, size_t ws_size,
                              hipStream_t stream) {
    const int B = 2, S = 2048, D = 1024, H = 16, F = 4096;
    const int M = B * S;  // 4096

    const float* x   = (const float*)d_in[0];
    const int*   mask= (const int*)  d_in[1];
    const float* wq  = (const float*)d_in[2];
    const float* bq  = (const float*)d_in[3];
    const float* wk  = (const float*)d_in[4];
    const float* bk  = (const float*)d_in[5];
    const float* wv  = (const float*)d_in[6];
    const float* bv  = (const float*)d_in[7];
    const float* wo  = (const float*)d_in[8];
    const float* bo  = (const float*)d_in[9];
    const float* g1  = (const float*)d_in[10];
    const float* be1 = (const float*)d_in[11];
    const float* g2  = (const float*)d_in[12];
    const float* be2 = (const float*)d_in[13];
    const float* w1  = (const float*)d_in[14];
    const float* bf1 = (const float*)d_in[15];
    const float* w2  = (const float*)d_in[16];
    const float* bf2 = (const float*)d_in[17];
    float* out = (float*)d_out;

    char* ws = (char*)d_ws;
    const size_t MB = 1024 * 1024;
    bf16* wqkvT = (bf16*)(ws + 0 * MB);            // [3072,1024]
    bf16* woT   = (bf16*)(ws + 6 * MB);
    bf16* w1T   = (bf16*)(ws + 8 * MB);
    bf16* w2T   = (bf16*)(ws + 16 * MB);
    bf16* xn    = (bf16*)(ws + 24 * MB);
    bf16* qkv   = (bf16*)(ws + 32 * MB);           // [4096,3072]
    bf16* att   = xn;                              // reuse
    // x2 (fp32 residual carrier) lives in d_out.

    const bool fullM = (ws_size >= 64 * MB);

    // fused weight transposes (1 launch, 12288 tiles)
    transpose_all<<<12288, 256, 0, stream>>>(wq, wk, wv, wo, w1, w2,
                                             wqkvT, woT, w1T, w2T);

    // LN1
    ln_kernel<float><<<M, 256, 0, stream>>>(x, g1, be1, xn, D);

    // fused QKV GEMM
    gemm_mfma<128, bf16, float, false, false, true><<<dim3(3072 / 128, M / 128), 256, 0, stream>>>(
        xn, wqkvT, bq, bk, bv, (const float*)nullptr, qkv, M, 3072, D);

    // attention (TQ=128)
    attn_mfma<<<dim3(S / 128, H, B), 256, 0, stream>>>(qkv, mask, att, B, S, 3072);

    // out-proj + residual(x fp32) -> x2 = d_out (fp32); BM=64 -> 512 blocks
    gemm_mfma<64, float, float, false, true, false><<<dim3(D / 128, M / 64), 256, 0, stream>>>(
        att, woT, bo, nullptr, nullptr, x, out, M, D, D);

    if (fullM) {
        bf16* hid = (bf16*)(ws + 24 * MB);   // [4096,4096] at [24,56)
        bf16* xn2 = (bf16*)(ws + 56 * MB);   // [4096,1024] at [56,64)
        ln_kernel<float><<<M, 256, 0, stream>>>(out, g2, be2, xn2, D);
        gemm_mfma<128, bf16, float, true, false, false><<<dim3(F / 128, M / 128), 256, 0, stream>>>(
            xn2, w1T, bf1, nullptr, nullptr, (const float*)nullptr, hid, M, F, D);
        gemm_mfma<64, float, float, false, true, false><<<dim3(D / 128, M / 64), 256, 0, stream>>>(
            hid, w2T, bf2, nullptr, nullptr, out, out, M, D, F);
    } else {
        bf16* xn2 = (bf16*)(ws + 32 * MB);   // q-section reuse
        bf16* hid = (bf16*)(ws + 40 * MB);   // k+v sections, [2048,4096]
        const int CH = 2048;
        ln_kernel<float><<<M, 256, 0, stream>>>(out, g2, be2, xn2, D);
        for (int c = 0; c < M / CH; ++c) {
            const size_t roff = (size_t)c * CH;
            gemm_mfma<128, bf16, float, true, false, false><<<dim3(F / 128, CH / 128), 256, 0, stream>>>(
                xn2 + roff * D, w1T, bf1, nullptr, nullptr, (const float*)nullptr, hid, CH, F, D);
            gemm_mfma<64, float, float, false, true, false><<<dim3(D / 128, CH / 64), 256, 0, stream>>>(
                hid, w2T, bf2, nullptr, nullptr, out + roff * D, out + roff * D, CH, D, F);
        }
    }
}

// Round 9
// 414.134 us; speedup vs baseline: 6.5523x; 1.0381x over previous
//
#include <hip/hip_runtime.h>
#include <hip/hip_bf16.h>

// Transformer block: LN1 -> QKV -> MHA(16 heads, hd=64) -> out-proj + resid
//                    -> LN2 -> FFN(4x, ReLU) + resid
// B=2, S=2048, D=1024, H=16, hd=64, F=4096. M = B*S = 4096.
// fp32 buffers in/out; bf16 intermediates (fp32 accumulation).
//
// Round 9:
//  (a) GEMM: BK 32->64 (halves the per-K barrier-drain count, the m97
//      structural stall) + XOR chunk swizzle on staging/reads. The old
//      As[.][32] layout made ds_read_b128 fragment reads 8-way bank
//      conflicted (row stride 16 dwords: banks (fr&1)*16+kg*4). Swizzle:
//      lane stages global chunk (l&7)^((l>>3)&7) so LDS slot c of row r
//      holds logical chunk c^(r&7); reads un-swizzle -> 2-way (free).
//      ks-batched fragment reads keep VGPR flat; LDS 32KB -> 3 blocks/CU.
//  (b) attention: log2e folded into Q pre-scale, exp2f (native v_exp_f32)
//      replaces __expf; P packed to bf16 by truncation (>>16) with l summing
//      the truncated values (consistent weights, ~10% VALU cut).

using bf16 = __hip_bfloat16;
typedef short bf16x8 __attribute__((ext_vector_type(8)));
typedef short bf16x4v __attribute__((ext_vector_type(4)));
typedef float f32x4 __attribute__((ext_vector_type(4)));

#if defined(__has_builtin)
#  if __has_builtin(__builtin_amdgcn_mfma_f32_16x16x16bf16_1k)
#    define HAVE_MFMA_K16 1
#  endif
#endif

__device__ __forceinline__ float toF(float v) { return v; }
__device__ __forceinline__ float toF(bf16 v) { return __bfloat162float(v); }
__device__ __forceinline__ void storeF(float* p, float v) { *p = v; }
__device__ __forceinline__ void storeF(bf16* p, float v) { *p = __float2bfloat16(v); }

__device__ __forceinline__ float waveReduceSum(float v) {
    #pragma unroll
    for (int o = 32; o > 0; o >>= 1) v += __shfl_down(v, o, 64);
    return v;
}

__device__ __forceinline__ void async16(const bf16* g, bf16* l) {
    __builtin_amdgcn_global_load_lds(
        (const __attribute__((address_space(1))) unsigned int*)g,
        (__attribute__((address_space(3))) unsigned int*)l,
        16, 0, 0);
}

__device__ __forceinline__ unsigned short bf16bits(float x) {
    union { bf16 h; unsigned short u; } e; e.h = __float2bfloat16(x);
    return e.u;
}

// ---------------- fused weight transpose + cast (all 6 weights) ------------
__global__ __launch_bounds__(256) void transpose_all(
        const float* __restrict__ wq, const float* __restrict__ wk,
        const float* __restrict__ wv, const float* __restrict__ wo,
        const float* __restrict__ w1, const float* __restrict__ w2,
        bf16* __restrict__ wqkvT, bf16* __restrict__ woT,
        bf16* __restrict__ w1T, bf16* __restrict__ w2T) {
    __shared__ float t[32][33];
    const int tI = blockIdx.x;
    const float* in; bf16* outT; int R, C, tl;
    if (tI < 4096) {
        const int seg = tI >> 10; tl = tI & 1023; R = 1024; C = 1024;
        in = (seg == 0) ? wq : (seg == 1) ? wk : (seg == 2) ? wv : wo;
        outT = (seg == 3) ? woT : wqkvT + (size_t)seg * 1024 * 1024;
    } else if (tI < 8192) {
        tl = tI - 4096; in = w1; outT = w1T; R = 1024; C = 4096;
    } else {
        tl = tI - 8192; in = w2; outT = w2T; R = 4096; C = 1024;
    }
    const int tc = C >> 5;
    const int c0 = (tl % tc) * 32, r0 = (tl / tc) * 32;
    const int lx = threadIdx.x & 31, ly = threadIdx.x >> 5;
    #pragma unroll
    for (int i = 0; i < 32; i += 8)
        t[ly + i][lx] = in[(size_t)(r0 + ly + i) * C + c0 + lx];
    __syncthreads();
    #pragma unroll
    for (int i = 0; i < 32; i += 8)
        outT[(size_t)(c0 + ly + i) * R + r0 + lx] = __float2bfloat16(t[lx][ly + i]);
}

// ---------------- LayerNorm: InT x -> bf16 out ----------------
template <typename InT>
__global__ __launch_bounds__(256) void ln_kernel(const InT* __restrict__ x,
                                                 const float* __restrict__ g,
                                                 const float* __restrict__ b,
                                                 bf16* __restrict__ out, int D) {
    const int row = blockIdx.x;
    const InT* xr = x + (size_t)row * D;
    float s = 0.f, s2 = 0.f;
    for (int i = threadIdx.x; i < D; i += 256) {
        float v = toF(xr[i]);
        s += v; s2 += v * v;
    }
    __shared__ float ws[4], ws2[4];
    int lane = threadIdx.x & 63, wid = threadIdx.x >> 6;
    s = waveReduceSum(s); s2 = waveReduceSum(s2);
    if (lane == 0) { ws[wid] = s; ws2[wid] = s2; }
    __syncthreads();
    float ts = ws[0] + ws[1] + ws[2] + ws[3];
    float ts2 = ws2[0] + ws2[1] + ws2[2] + ws2[3];
    float mean = ts / D;
    float var = ts2 / D - mean * mean;
    float rstd = rsqrtf(var + 1e-5f);
    bf16* outr = out + (size_t)row * D;
    for (int i = threadIdx.x; i < D; i += 256) {
        float v = (toF(xr[i]) - mean) * rstd * g[i] + b[i];
        outr[i] = __float2bfloat16(v);
    }
}

// ---------------- MFMA GEMM: C = act(A @ BT^T + bias) [+ resid] ------------
// BK=64, XOR-swizzled LDS (chunk c of row r stored at slot c^(r&7)).
// BM = 128 (waves 2x2, 64x64 each) or 64 (waves 2x2, 32x64 each). BN=128.
template <int BM, typename OutT, typename ResidT, bool RELU, bool HAS_RESID, bool BIAS3>
__global__ __launch_bounds__(256) void gemm_mfma(const bf16* __restrict__ A,
                                                 const bf16* __restrict__ BT,
                                                 const float* __restrict__ bias,
                                                 const float* __restrict__ biasK,
                                                 const float* __restrict__ biasV,
                                                 const ResidT* __restrict__ resid,
                                                 OutT* __restrict__ C,
                                                 int M, int N, int K) {
    constexpr int BK = 64;
    constexpr int MI = BM / 32;      // m-frags per wave (4 or 2)
    constexpr int AROWS = BM / 4;    // A rows staged per wave (32 or 16)
    constexpr int ASEC = AROWS / 8;  // async16 sections for A (4 or 2)
    __shared__ bf16 As[BM][BK];      // row stride 128 B
    __shared__ bf16 Bs[128][BK];
    const int tid = threadIdx.x, lane = tid & 63, wid = tid >> 6;
    const int m0 = blockIdx.y * BM, n0 = blockIdx.x * 128;
    const int wm = (BM == 128) ? (wid >> 1) * 64 : (wid & 1) * 32;
    const int wn = (BM == 128) ? (wid & 1) * 64 : (wid >> 1) * 64;

    f32x4 acc[MI][4] = {};

    // staging: lane l covers row (l>>3) of an 8-row section, physical chunk
    // l&7; it must fetch LOGICAL chunk (l&7)^(l>>3) so slot c holds c^(r&7).
    const int srow = lane >> 3;
    const int scol = ((lane & 7) ^ srow) * 8;       // logical elem offset
    const bf16* Abase = A + (size_t)(m0 + wid * AROWS + srow) * K + scol;
    const bf16* Bbase = BT + (size_t)(n0 + wid * 32 + srow) * K + scol;

    const int fr = lane & 15;
    const int kg = lane >> 4;

    for (int k0 = 0; k0 < K; k0 += BK) {
        #pragma unroll
        for (int s = 0; s < ASEC; ++s)
            async16(Abase + (size_t)(s * 8) * K + k0, &As[wid * AROWS + s * 8][0]);
        #pragma unroll
        for (int s = 0; s < 4; ++s)
            async16(Bbase + (size_t)(s * 8) * K + k0, &Bs[wid * 32 + s * 8][0]);
        __syncthreads();

        #pragma unroll
        for (int ks = 0; ks < 2; ++ks) {
            // logical chunk ks*4+kg, un-swizzle with row (fr&7)
            const int pc = ((ks * 4 + kg) ^ (fr & 7)) * 16;   // byte offset
            bf16x8 aF[MI], bF[4];
            #pragma unroll
            for (int i = 0; i < MI; ++i)
                aF[i] = *(const bf16x8*)((const char*)&As[0][0]
                         + (size_t)(wm + i * 16 + fr) * 128 + pc);
            #pragma unroll
            for (int j = 0; j < 4; ++j)
                bF[j] = *(const bf16x8*)((const char*)&Bs[0][0]
                         + (size_t)(wn + j * 16 + fr) * 128 + pc);
            #pragma unroll
            for (int i = 0; i < MI; ++i)
                #pragma unroll
                for (int j = 0; j < 4; ++j)
                    acc[i][j] = __builtin_amdgcn_mfma_f32_16x16x32_bf16(
                        aF[i], bF[j], acc[i][j], 0, 0, 0);
        }
        __syncthreads();
    }

    const int col_l = lane & 15, row_l = (lane >> 4) * 4;
    #pragma unroll
    for (int j = 0; j < 4; ++j) {
        const int col = n0 + wn + j * 16 + col_l;
        float bvv;
        if (BIAS3) {
            const float* bp = (col < 1024) ? bias : ((col < 2048) ? biasK : biasV);
            bvv = bp[col & 1023];
        } else {
            bvv = bias[col];
        }
        #pragma unroll
        for (int i = 0; i < MI; ++i) {
            #pragma unroll
            for (int r = 0; r < 4; ++r) {
                const int row = m0 + wm + i * 16 + row_l + r;
                float v = acc[i][j][r] + bvv;
                if (RELU) v = fmaxf(v, 0.f);
                if (HAS_RESID) v += toF(resid[(size_t)row * N + col]);
                storeF(&C[(size_t)row * N + col], v);
            }
        }
    }
}

// ---------------- MFMA flash attention, S^T formulation, TQ=128 ------------
// grid (S/128, H, B), block 256 = 4 waves; wave w owns q-rows [w*32,w*32+32)
// as two 16-q groups. Softmax in log2 domain (log2e folded into Q scale).
#if HAVE_MFMA_K16
__global__ __launch_bounds__(256) void attn_mfma(const bf16* __restrict__ qkv,
                                                 const int* __restrict__ mask,
                                                 bf16* __restrict__ outp,
                                                 int B, int S, int LD) {
    const int q0 = blockIdx.x * 128;
    const int h = blockIdx.y, b = blockIdx.z;
    const int Do = 1024;
    const int tid = threadIdx.x, lane = tid & 63, wid = tid >> 6;
    const int n = lane & 15, kg = lane >> 4;

    __shared__ bf16 Ks[64][66];     // K tile [j][d], 132B rows
    __shared__ bf16 Vt[64][68];     // V^T tile [d][j], 136B rows
    __shared__ float Mskf[64];      // additive mask bias (log2 domain ok)

    // Q B-frags, pre-scaled by (1/sqrt(64))*log2(e)
    const float QSCALE = 0.125f * 1.4426950408889634f;
    bf16x8 qf[2][2];
    #pragma unroll
    for (int u = 0; u < 2; ++u) {
        const bf16* qp = qkv + ((size_t)(b * S + q0 + wid * 32 + u * 16 + n)) * LD + h * 64 + kg * 8;
        union { uint4 uu; bf16x8 v; unsigned short s[8]; } c[2];
        c[0].uu = *(const uint4*)qp;
        c[1].uu = *(const uint4*)(qp + 32);
        #pragma unroll
        for (int t = 0; t < 2; ++t) {
            #pragma unroll
            for (int i = 0; i < 8; ++i) {
                union { float f; unsigned int u2; } d;
                d.u2 = ((unsigned int)c[t].s[i]) << 16;
                c[t].s[i] = bf16bits(d.f * QSCALE);
            }
            qf[u][t] = c[t].v;
        }
    }

    f32x4 acc[2][4] = {};
    float m[2] = {-1e30f, -1e30f}, l[2] = {0.f, 0.f};

    const int sr = tid >> 2, sc = (tid & 3) * 16;   // K staging
    const int jp = tid & 31, dg = (tid >> 5) * 8;   // V staging
    const bf16* kbase = qkv + (size_t)(b * S) * LD + 1024 + h * 64;
    const bf16* vbase = qkv + (size_t)(b * S) * LD + 2048 + h * 64;

    for (int j0 = 0; j0 < S; j0 += 64) {
        __syncthreads();
        {
            const bf16* kp = kbase + (size_t)(j0 + sr) * LD + sc;
            uint4 ka = *(const uint4*)kp;
            uint4 kc = *(const uint4*)(kp + 8);
            uint* kd = (uint*)((char*)&Ks[0][0] + sr * 132 + sc * 2);
            kd[0] = ka.x; kd[1] = ka.y; kd[2] = ka.z; kd[3] = ka.w;
            kd[4] = kc.x; kd[5] = kc.y; kd[6] = kc.z; kd[7] = kc.w;

            const bf16* vp = vbase + (size_t)(j0 + 2 * jp) * LD + dg;
            union { uint4 u; unsigned short s[8]; } va, vc;
            va.u = *(const uint4*)vp;
            vc.u = *(const uint4*)(vp + LD);
            #pragma unroll
            for (int i = 0; i < 8; ++i) {
                unsigned int pk = (unsigned int)va.s[i] | ((unsigned int)vc.s[i] << 16);
                *(unsigned int*)((char*)&Vt[0][0] + (size_t)(dg + i) * 136 + jp * 4) = pk;
            }
            if (tid < 64) Mskf[tid] = (mask[b * S + j0 + tid] == 0) ? -1e9f : 0.f;
        }
        __syncthreads();

        // ---- S^T = K @ Q^T (log2-scaled); K-frags read once ----
        f32x4 st[2][4] = {};
        #pragma unroll
        for (int ks = 0; ks < 2; ++ks) {
            #pragma unroll
            for (int jt = 0; jt < 4; ++jt) {
                union { uint u[4]; bf16x8 v; } kf;
                const uint* bp = (const uint*)((const char*)&Ks[0][0]
                                 + (size_t)(jt * 16 + n) * 132 + ks * 64 + kg * 16);
                kf.u[0] = bp[0]; kf.u[1] = bp[1]; kf.u[2] = bp[2]; kf.u[3] = bp[3];
                st[0][jt] = __builtin_amdgcn_mfma_f32_16x16x32_bf16(kf.v, qf[0][ks], st[0][jt], 0, 0, 0);
                st[1][jt] = __builtin_amdgcn_mfma_f32_16x16x32_bf16(kf.v, qf[1][ks], st[1][jt], 0, 0, 0);
            }
        }

        // ---- online softmax per group (exp2, truncation-packed P) ----
        bf16x4v pf[2][4];
        #pragma unroll
        for (int u = 0; u < 2; ++u) {
            float mx = m[u];
            #pragma unroll
            for (int jt = 0; jt < 4; ++jt) {
                f32x4 mb = *(const f32x4*)&Mskf[jt * 16 + kg * 4];
                #pragma unroll
                for (int r = 0; r < 4; ++r) {
                    st[u][jt][r] += mb[r];
                    mx = fmaxf(mx, st[u][jt][r]);
                }
            }
            mx = fmaxf(mx, __shfl_xor(mx, 16, 64));
            mx = fmaxf(mx, __shfl_xor(mx, 32, 64));
            float alpha = exp2f(m[u] - mx);
            m[u] = mx;
            float ls = 0.f;
            #pragma unroll
            for (int jt = 0; jt < 4; ++jt) {
                union { unsigned short s[4]; bf16x4v v; } pk;
                #pragma unroll
                for (int r = 0; r < 4; ++r) {
                    union { float f; unsigned int u2; } p;
                    p.f = exp2f(st[u][jt][r] - mx);
                    p.u2 &= 0xffff0000u;          // truncate to bf16
                    ls += p.f;                    // sum the truncated value
                    pk.s[r] = (unsigned short)(p.u2 >> 16);
                }
                pf[u][jt] = pk.v;
            }
            ls += __shfl_xor(ls, 16, 64);
            ls += __shfl_xor(ls, 32, 64);
            l[u] = l[u] * alpha + ls;
            #pragma unroll
            for (int dt = 0; dt < 4; ++dt)
                #pragma unroll
                for (int r = 0; r < 4; ++r) acc[u][dt][r] *= alpha;
        }

        // ---- O^T += V^T @ P^T; V-frags read once ----
        #pragma unroll
        for (int jt = 0; jt < 4; ++jt) {
            #pragma unroll
            for (int dt = 0; dt < 4; ++dt) {
                union { uint u[2]; bf16x4v v; } vf;
                const uint* vpp = (const uint*)((const char*)&Vt[0][0]
                                  + (size_t)(dt * 16 + n) * 136 + jt * 32 + kg * 8);
                vf.u[0] = vpp[0]; vf.u[1] = vpp[1];
                acc[0][dt] = __builtin_amdgcn_mfma_f32_16x16x16bf16_1k(vf.v, pf[0][jt], acc[0][dt], 0, 0, 0);
                acc[1][dt] = __builtin_amdgcn_mfma_f32_16x16x16bf16_1k(vf.v, pf[1][jt], acc[1][dt], 0, 0, 0);
            }
        }
    }

    // ---- epilogue ----
    #pragma unroll
    for (int u = 0; u < 2; ++u) {
        float inv = (l[u] > 0.f) ? (1.f / l[u]) : 0.f;
        bf16* op = outp + ((size_t)(b * S + q0 + wid * 32 + u * 16 + n)) * Do + h * 64;
        #pragma unroll
        for (int dt = 0; dt < 4; ++dt) {
            union { unsigned short s[4]; uint2 u2; } w;
            #pragma unroll
            for (int r = 0; r < 4; ++r) w.s[r] = bf16bits(acc[u][dt][r] * inv);
            *(uint2*)(op + dt * 16 + kg * 4) = w.u2;
        }
    }
}
#else
// Fallback (round-5 structure); handles 128 q-rows as two sequential halves.
__global__ __launch_bounds__(256) void attn_mfma(const bf16* __restrict__ qkv,
                                                 const int* __restrict__ mask,
                                                 bf16* __restrict__ outp,
                                                 int B, int S, int LD) {
    const int h = blockIdx.y, b = blockIdx.z;
    const int Do = 1024;
    const int tid = threadIdx.x, lane = tid & 63, wid = tid >> 6;
    const int n = lane & 15, kg = lane >> 4;

    __shared__ bf16 Ks[64][66];
    __shared__ bf16 Vt[64][66];
    __shared__ bf16 Plds[4][16][66];
    __shared__ int  Msk[64];

    for (int half = 0; half < 2; ++half) {
        const int q0 = blockIdx.x * 128 + half * 64;
        __syncthreads();

        bf16x8 qf[2];
        {
            const bf16* qp = qkv + ((size_t)(b * S + q0 + wid * 16 + n)) * LD + h * 64 + kg * 8;
            union { uint4 u; bf16x8 v; } c0, c1;
            c0.u = *(const uint4*)qp;
            c1.u = *(const uint4*)(qp + 32);
            qf[0] = c0.v; qf[1] = c1.v;
        }

        f32x4 acc_o[4] = {};
        float m_r[4] = {-1e30f, -1e30f, -1e30f, -1e30f};
        float l_r[4] = {0.f, 0.f, 0.f, 0.f};

        const int sr = tid >> 2;
        const int sc = (tid & 3) * 16;
        const bf16* kbase = qkv + (size_t)(b * S) * LD + 1024 + h * 64;
        const bf16* vbase = qkv + (size_t)(b * S) * LD + 2048 + h * 64;

        for (int j0 = 0; j0 < S; j0 += 64) {
            __syncthreads();
            {
                const bf16* kp = kbase + (size_t)(j0 + sr) * LD + sc;
                uint4 ka = *(const uint4*)kp;
                uint4 kbv = *(const uint4*)(kp + 8);
                uint* kd = (uint*)((char*)&Ks[0][0] + sr * 132 + sc * 2);
                kd[0] = ka.x; kd[1] = ka.y; kd[2] = ka.z; kd[3] = ka.w;
                kd[4] = kbv.x; kd[5] = kbv.y; kd[6] = kbv.z; kd[7] = kbv.w;

                const bf16* vp = vbase + (size_t)(j0 + sr) * LD + sc;
                union { uint4 u[2]; unsigned short s[16]; } vv;
                vv.u[0] = *(const uint4*)vp;
                vv.u[1] = *(const uint4*)(vp + 8);
                #pragma unroll
                for (int i = 0; i < 16; ++i)
                    *((unsigned short*)((char*)&Vt[0][0] + (size_t)(sc + i) * 132 + sr * 2)) = vv.s[i];

                if (tid < 64) Msk[tid] = mask[b * S + j0 + tid];
            }
            __syncthreads();

            f32x4 st[4] = {};
            #pragma unroll
            for (int ks = 0; ks < 2; ++ks) {
                #pragma unroll
                for (int jt = 0; jt < 4; ++jt) {
                    union { uint u[4]; bf16x8 v; } bf;
                    const uint* bp = (const uint*)((const char*)&Ks[0][0]
                                     + (size_t)(jt * 16 + n) * 132 + ks * 64 + kg * 16);
                    bf.u[0] = bp[0]; bf.u[1] = bp[1]; bf.u[2] = bp[2]; bf.u[3] = bp[3];
                    st[jt] = __builtin_amdgcn_mfma_f32_16x16x32_bf16(qf[ks], bf.v, st[jt], 0, 0, 0);
                }
            }

            int mk[4];
            #pragma unroll
            for (int jt = 0; jt < 4; ++jt) mk[jt] = Msk[jt * 16 + n];

            #pragma unroll
            for (int r = 0; r < 4; ++r) {
                float mx = -1e30f;
                #pragma unroll
                for (int jt = 0; jt < 4; ++jt) {
                    float s = st[jt][r] * 0.125f;
                    if (mk[jt] == 0) s = -1e9f;
                    st[jt][r] = s;
                    mx = fmaxf(mx, s);
                }
                #pragma unroll
                for (int o = 1; o < 16; o <<= 1) mx = fmaxf(mx, __shfl_xor(mx, o, 64));
                float newm = fmaxf(m_r[r], mx);
                float alpha = __expf(m_r[r] - newm);
                m_r[r] = newm;
                float ls = 0.f;
                #pragma unroll
                for (int jt = 0; jt < 4; ++jt) {
                    float p = __expf(st[jt][r] - newm);
                    ls += p;
                    Plds[wid][kg * 4 + r][jt * 16 + n] = __float2bfloat16(p);
                }
                #pragma unroll
                for (int o = 1; o < 16; o <<= 1) ls += __shfl_xor(ls, o, 64);
                l_r[r] = l_r[r] * alpha + ls;
                #pragma unroll
                for (int dt = 0; dt < 4; ++dt) acc_o[dt][r] *= alpha;
            }

            __asm__ volatile("s_waitcnt lgkmcnt(0)" ::: "memory");

            #pragma unroll
            for (int ks = 0; ks < 2; ++ks) {
                union { uint u[4]; bf16x8 v; } af;
                const uint* ap = (const uint*)((const char*)&Plds[wid][0][0]
                                 + (size_t)n * 132 + ks * 64 + kg * 16);
                af.u[0] = ap[0]; af.u[1] = ap[1]; af.u[2] = ap[2]; af.u[3] = ap[3];
                #pragma unroll
                for (int dt = 0; dt < 4; ++dt) {
                    union { uint u[4]; bf16x8 v; } bf;
                    const uint* bp = (const uint*)((const char*)&Vt[0][0]
                                     + (size_t)(dt * 16 + n) * 132 + ks * 64 + kg * 16);
                    bf.u[0] = bp[0]; bf.u[1] = bp[1]; bf.u[2] = bp[2]; bf.u[3] = bp[3];
                    acc_o[dt] = __builtin_amdgcn_mfma_f32_16x16x32_bf16(af.v, bf.v, acc_o[dt], 0, 0, 0);
                }
            }
        }

        #pragma unroll
        for (int r = 0; r < 4; ++r) {
            float inv = (l_r[r] > 0.f) ? (1.f / l_r[r]) : 0.f;
            bf16* op = outp + ((size_t)(b * S + q0 + wid * 16 + kg * 4 + r)) * Do + h * 64 + n;
            #pragma unroll
            for (int dt = 0; dt < 4; ++dt)
                op[dt * 16] = __float2bfloat16(acc_o[dt][r] * inv);
        }
    }
}
#endif

extern "C" void kernel_launch(void* const* d_in, const int* in_sizes, int n_in,
                              void* d_out, int out_size, void* d_ws, size_t ws_size,
                              hipStream_t stream) {
    const int B = 2, S = 2048, D = 1024, H = 16, F = 4096;
    const int M = B * S;  // 4096

    const float* x   = (const float*)d_in[0];
    const int*   mask= (const int*)  d_in[1];
    const float* wq  = (const float*)d_in[2];
    const float* bq  = (const float*)d_in[3];
    const float* wk  = (const float*)d_in[4];
    const float* bk  = (const float*)d_in[5];
    const float* wv  = (const float*)d_in[6];
    const float* bv  = (const float*)d_in[7];
    const float* wo  = (const float*)d_in[8];
    const float* bo  = (const float*)d_in[9];
    const float* g1  = (const float*)d_in[10];
    const float* be1 = (const float*)d_in[11];
    const float* g2  = (const float*)d_in[12];
    const float* be2 = (const float*)d_in[13];
    const float* w1  = (const float*)d_in[14];
    const float* bf1 = (const float*)d_in[15];
    const float* w2  = (const float*)d_in[16];
    const float* bf2 = (const float*)d_in[17];
    float* out = (float*)d_out;

    char* ws = (char*)d_ws;
    const size_t MB = 1024 * 1024;
    bf16* wqkvT = (bf16*)(ws + 0 * MB);            // [3072,1024]
    bf16* woT   = (bf16*)(ws + 6 * MB);
    bf16* w1T   = (bf16*)(ws + 8 * MB);
    bf16* w2T   = (bf16*)(ws + 16 * MB);
    bf16* xn    = (bf16*)(ws + 24 * MB);
    bf16* qkv   = (bf16*)(ws + 32 * MB);           // [4096,3072]
    bf16* att   = xn;                              // reuse
    // x2 (fp32 residual carrier) lives in d_out.

    const bool fullM = (ws_size >= 64 * MB);

    transpose_all<<<12288, 256, 0, stream>>>(wq, wk, wv, wo, w1, w2,
                                             wqkvT, woT, w1T, w2T);

    ln_kernel<float><<<M, 256, 0, stream>>>(x, g1, be1, xn, D);

    gemm_mfma<128, bf16, float, false, false, true><<<dim3(3072 / 128, M / 128), 256, 0, stream>>>(
        xn, wqkvT, bq, bk, bv, (const float*)nullptr, qkv, M, 3072, D);

    attn_mfma<<<dim3(S / 128, H, B), 256, 0, stream>>>(qkv, mask, att, B, S, 3072);

    gemm_mfma<64, float, float, false, true, false><<<dim3(D / 128, M / 64), 256, 0, stream>>>(
        att, woT, bo, nullptr, nullptr, x, out, M, D, D);

    if (fullM) {
        bf16* hid = (bf16*)(ws + 24 * MB);   // [4096,4096] at [24,56)
        bf16* xn2 = (bf16*)(ws + 56 * MB);   // [4096,1024] at [56,64)
        ln_kernel<float><<<M, 256, 0, stream>>>(out, g2, be2, xn2, D);
        gemm_mfma<128, bf16, float, true, false, false><<<dim3(F / 128, M / 128), 256, 0, stream>>>(
            xn2, w1T, bf1, nullptr, nullptr, (const float*)nullptr, hid, M, F, D);
        gemm_mfma<64, float, float, false, true, false><<<dim3(D / 128, M / 64), 256, 0, stream>>>(
            hid, w2T, bf2, nullptr, nullptr, out, out, M, D, F);
    } else {
        bf16* xn2 = (bf16*)(ws + 32 * MB);   // q-section reuse
        bf16* hid = (bf16*)(ws + 40 * MB);   // k+v sections, [2048,4096]
        const int CH = 2048;
        ln_kernel<float><<<M, 256, 0, stream>>>(out, g2, be2, xn2, D);
        for (int c = 0; c < M / CH; ++c) {
            const size_t roff = (size_t)c * CH;
            gemm_mfma<128, bf16, float, true, false, false><<<dim3(F / 128, CH / 128), 256, 0, stream>>>(
                xn2 + roff * D, w1T, bf1, nullptr, nullptr, (const float*)nullptr, hid, CH, F, D);
            gemm_mfma<64, float, float, false, true, false><<<dim3(D / 128, CH / 64), 256, 0, stream>>>(
                hid, w2T, bf2, nullptr, nullptr, out + roff * D, out + roff * D, CH, D, F);
        }
    }
}

// Round 10
// 397.759 us; speedup vs baseline: 6.8221x; 1.0412x over previous
//
#include <hip/hip_runtime.h>
#include <hip/hip_bf16.h>

// Transformer block: LN1 -> QKV -> MHA(16 heads, hd=64) -> out-proj + resid
//                    -> LN2 -> FFN(4x, ReLU) + resid
// B=2, S=2048, D=1024, H=16, hd=64, F=4096. M = B*S = 4096.
// fp32 buffers in/out; bf16 intermediates (fp32 accumulation).
//
// Round 10: fix the round-9 attention regression. exp2f() lowers to
// __ocml_exp2_f32 (software, multi-instruction), NOT v_exp_f32 — that added
// ~19us of VALU to a VALU-bound kernel. Use __builtin_amdgcn_exp2f (native
// v_exp_f32). Log2-domain softmax kept (Q pre-scaled by log2e/8).
// GEMM pipeline unchanged from round 9 (BK=64 + XOR chunk swizzle: staging
// lane l fetches logical chunk (l&7)^(l>>3); slot c of row r holds c^(r&7);
// reads un-swizzle via ((ks*4+kg)^(fr&7)) -> 2-way banks, free).

using bf16 = __hip_bfloat16;
typedef short bf16x8 __attribute__((ext_vector_type(8)));
typedef short bf16x4v __attribute__((ext_vector_type(4)));
typedef float f32x4 __attribute__((ext_vector_type(4)));

#if defined(__has_builtin)
#  if __has_builtin(__builtin_amdgcn_mfma_f32_16x16x16bf16_1k)
#    define HAVE_MFMA_K16 1
#  endif
#  if __has_builtin(__builtin_amdgcn_exp2f)
#    define EXP2F(x) __builtin_amdgcn_exp2f(x)
#  endif
#endif
#ifndef EXP2F
#  define EXP2F(x) __expf(0.6931471805599453f * (x))
#endif

__device__ __forceinline__ float toF(float v) { return v; }
__device__ __forceinline__ float toF(bf16 v) { return __bfloat162float(v); }
__device__ __forceinline__ void storeF(float* p, float v) { *p = v; }
__device__ __forceinline__ void storeF(bf16* p, float v) { *p = __float2bfloat16(v); }

__device__ __forceinline__ float waveReduceSum(float v) {
    #pragma unroll
    for (int o = 32; o > 0; o >>= 1) v += __shfl_down(v, o, 64);
    return v;
}

__device__ __forceinline__ void async16(const bf16* g, bf16* l) {
    __builtin_amdgcn_global_load_lds(
        (const __attribute__((address_space(1))) unsigned int*)g,
        (__attribute__((address_space(3))) unsigned int*)l,
        16, 0, 0);
}

__device__ __forceinline__ unsigned short bf16bits(float x) {
    union { bf16 h; unsigned short u; } e; e.h = __float2bfloat16(x);
    return e.u;
}

// ---------------- fused weight transpose + cast (all 6 weights) ------------
__global__ __launch_bounds__(256) void transpose_all(
        const float* __restrict__ wq, const float* __restrict__ wk,
        const float* __restrict__ wv, const float* __restrict__ wo,
        const float* __restrict__ w1, const float* __restrict__ w2,
        bf16* __restrict__ wqkvT, bf16* __restrict__ woT,
        bf16* __restrict__ w1T, bf16* __restrict__ w2T) {
    __shared__ float t[32][33];
    const int tI = blockIdx.x;
    const float* in; bf16* outT; int R, C, tl;
    if (tI < 4096) {
        const int seg = tI >> 10; tl = tI & 1023; R = 1024; C = 1024;
        in = (seg == 0) ? wq : (seg == 1) ? wk : (seg == 2) ? wv : wo;
        outT = (seg == 3) ? woT : wqkvT + (size_t)seg * 1024 * 1024;
    } else if (tI < 8192) {
        tl = tI - 4096; in = w1; outT = w1T; R = 1024; C = 4096;
    } else {
        tl = tI - 8192; in = w2; outT = w2T; R = 4096; C = 1024;
    }
    const int tc = C >> 5;
    const int c0 = (tl % tc) * 32, r0 = (tl / tc) * 32;
    const int lx = threadIdx.x & 31, ly = threadIdx.x >> 5;
    #pragma unroll
    for (int i = 0; i < 32; i += 8)
        t[ly + i][lx] = in[(size_t)(r0 + ly + i) * C + c0 + lx];
    __syncthreads();
    #pragma unroll
    for (int i = 0; i < 32; i += 8)
        outT[(size_t)(c0 + ly + i) * R + r0 + lx] = __float2bfloat16(t[lx][ly + i]);
}

// ---------------- LayerNorm: InT x -> bf16 out ----------------
template <typename InT>
__global__ __launch_bounds__(256) void ln_kernel(const InT* __restrict__ x,
                                                 const float* __restrict__ g,
                                                 const float* __restrict__ b,
                                                 bf16* __restrict__ out, int D) {
    const int row = blockIdx.x;
    const InT* xr = x + (size_t)row * D;
    float s = 0.f, s2 = 0.f;
    for (int i = threadIdx.x; i < D; i += 256) {
        float v = toF(xr[i]);
        s += v; s2 += v * v;
    }
    __shared__ float ws[4], ws2[4];
    int lane = threadIdx.x & 63, wid = threadIdx.x >> 6;
    s = waveReduceSum(s); s2 = waveReduceSum(s2);
    if (lane == 0) { ws[wid] = s; ws2[wid] = s2; }
    __syncthreads();
    float ts = ws[0] + ws[1] + ws[2] + ws[3];
    float ts2 = ws2[0] + ws2[1] + ws2[2] + ws2[3];
    float mean = ts / D;
    float var = ts2 / D - mean * mean;
    float rstd = rsqrtf(var + 1e-5f);
    bf16* outr = out + (size_t)row * D;
    for (int i = threadIdx.x; i < D; i += 256) {
        float v = (toF(xr[i]) - mean) * rstd * g[i] + b[i];
        outr[i] = __float2bfloat16(v);
    }
}

// ---------------- MFMA GEMM: C = act(A @ BT^T + bias) [+ resid] ------------
// BK=64, XOR-swizzled LDS (chunk c of row r stored at slot c^(r&7)).
template <int BM, typename OutT, typename ResidT, bool RELU, bool HAS_RESID, bool BIAS3>
__global__ __launch_bounds__(256) void gemm_mfma(const bf16* __restrict__ A,
                                                 const bf16* __restrict__ BT,
                                                 const float* __restrict__ bias,
                                                 const float* __restrict__ biasK,
                                                 const float* __restrict__ biasV,
                                                 const ResidT* __restrict__ resid,
                                                 OutT* __restrict__ C,
                                                 int M, int N, int K) {
    constexpr int BK = 64;
    constexpr int MI = BM / 32;
    constexpr int AROWS = BM / 4;
    constexpr int ASEC = AROWS / 8;
    __shared__ bf16 As[BM][BK];      // row stride 128 B
    __shared__ bf16 Bs[128][BK];
    const int tid = threadIdx.x, lane = tid & 63, wid = tid >> 6;
    const int m0 = blockIdx.y * BM, n0 = blockIdx.x * 128;
    const int wm = (BM == 128) ? (wid >> 1) * 64 : (wid & 1) * 32;
    const int wn = (BM == 128) ? (wid & 1) * 64 : (wid >> 1) * 64;

    f32x4 acc[MI][4] = {};

    const int srow = lane >> 3;
    const int scol = ((lane & 7) ^ srow) * 8;
    const bf16* Abase = A + (size_t)(m0 + wid * AROWS + srow) * K + scol;
    const bf16* Bbase = BT + (size_t)(n0 + wid * 32 + srow) * K + scol;

    const int fr = lane & 15;
    const int kg = lane >> 4;

    for (int k0 = 0; k0 < K; k0 += BK) {
        #pragma unroll
        for (int s = 0; s < ASEC; ++s)
            async16(Abase + (size_t)(s * 8) * K + k0, &As[wid * AROWS + s * 8][0]);
        #pragma unroll
        for (int s = 0; s < 4; ++s)
            async16(Bbase + (size_t)(s * 8) * K + k0, &Bs[wid * 32 + s * 8][0]);
        __syncthreads();

        #pragma unroll
        for (int ks = 0; ks < 2; ++ks) {
            const int pc = ((ks * 4 + kg) ^ (fr & 7)) * 16;
            bf16x8 aF[MI], bF[4];
            #pragma unroll
            for (int i = 0; i < MI; ++i)
                aF[i] = *(const bf16x8*)((const char*)&As[0][0]
                         + (size_t)(wm + i * 16 + fr) * 128 + pc);
            #pragma unroll
            for (int j = 0; j < 4; ++j)
                bF[j] = *(const bf16x8*)((const char*)&Bs[0][0]
                         + (size_t)(wn + j * 16 + fr) * 128 + pc);
            #pragma unroll
            for (int i = 0; i < MI; ++i)
                #pragma unroll
                for (int j = 0; j < 4; ++j)
                    acc[i][j] = __builtin_amdgcn_mfma_f32_16x16x32_bf16(
                        aF[i], bF[j], acc[i][j], 0, 0, 0);
        }
        __syncthreads();
    }

    const int col_l = lane & 15, row_l = (lane >> 4) * 4;
    #pragma unroll
    for (int j = 0; j < 4; ++j) {
        const int col = n0 + wn + j * 16 + col_l;
        float bvv;
        if (BIAS3) {
            const float* bp = (col < 1024) ? bias : ((col < 2048) ? biasK : biasV);
            bvv = bp[col & 1023];
        } else {
            bvv = bias[col];
        }
        #pragma unroll
        for (int i = 0; i < MI; ++i) {
            #pragma unroll
            for (int r = 0; r < 4; ++r) {
                const int row = m0 + wm + i * 16 + row_l + r;
                float v = acc[i][j][r] + bvv;
                if (RELU) v = fmaxf(v, 0.f);
                if (HAS_RESID) v += toF(resid[(size_t)row * N + col]);
                storeF(&C[(size_t)row * N + col], v);
            }
        }
    }
}

// ---------------- MFMA flash attention, S^T formulation, TQ=128 ------------
#if HAVE_MFMA_K16
__global__ __launch_bounds__(256) void attn_mfma(const bf16* __restrict__ qkv,
                                                 const int* __restrict__ mask,
                                                 bf16* __restrict__ outp,
                                                 int B, int S, int LD) {
    const int q0 = blockIdx.x * 128;
    const int h = blockIdx.y, b = blockIdx.z;
    const int Do = 1024;
    const int tid = threadIdx.x, lane = tid & 63, wid = tid >> 6;
    const int n = lane & 15, kg = lane >> 4;

    __shared__ bf16 Ks[64][66];     // K tile [j][d], 132B rows
    __shared__ bf16 Vt[64][68];     // V^T tile [d][j], 136B rows
    __shared__ float Mskf[64];      // additive mask bias (log2 domain)

    // Q B-frags, pre-scaled by (1/sqrt(64))*log2(e)
    const float QSCALE = 0.125f * 1.4426950408889634f;
    bf16x8 qf[2][2];
    #pragma unroll
    for (int u = 0; u < 2; ++u) {
        const bf16* qp = qkv + ((size_t)(b * S + q0 + wid * 32 + u * 16 + n)) * LD + h * 64 + kg * 8;
        union { uint4 uu; bf16x8 v; unsigned short s[8]; } c[2];
        c[0].uu = *(const uint4*)qp;
        c[1].uu = *(const uint4*)(qp + 32);
        #pragma unroll
        for (int t = 0; t < 2; ++t) {
            #pragma unroll
            for (int i = 0; i < 8; ++i) {
                union { float f; unsigned int u2; } d;
                d.u2 = ((unsigned int)c[t].s[i]) << 16;
                c[t].s[i] = bf16bits(d.f * QSCALE);
            }
            qf[u][t] = c[t].v;
        }
    }

    f32x4 acc[2][4] = {};
    float m[2] = {-1e30f, -1e30f}, l[2] = {0.f, 0.f};

    const int sr = tid >> 2, sc = (tid & 3) * 16;
    const int jp = tid & 31, dg = (tid >> 5) * 8;
    const bf16* kbase = qkv + (size_t)(b * S) * LD + 1024 + h * 64;
    const bf16* vbase = qkv + (size_t)(b * S) * LD + 2048 + h * 64;

    for (int j0 = 0; j0 < S; j0 += 64) {
        __syncthreads();
        {
            const bf16* kp = kbase + (size_t)(j0 + sr) * LD + sc;
            uint4 ka = *(const uint4*)kp;
            uint4 kc = *(const uint4*)(kp + 8);
            uint* kd = (uint*)((char*)&Ks[0][0] + sr * 132 + sc * 2);
            kd[0] = ka.x; kd[1] = ka.y; kd[2] = ka.z; kd[3] = ka.w;
            kd[4] = kc.x; kd[5] = kc.y; kd[6] = kc.z; kd[7] = kc.w;

            const bf16* vp = vbase + (size_t)(j0 + 2 * jp) * LD + dg;
            union { uint4 u; unsigned short s[8]; } va, vc;
            va.u = *(const uint4*)vp;
            vc.u = *(const uint4*)(vp + LD);
            #pragma unroll
            for (int i = 0; i < 8; ++i) {
                unsigned int pk = (unsigned int)va.s[i] | ((unsigned int)vc.s[i] << 16);
                *(unsigned int*)((char*)&Vt[0][0] + (size_t)(dg + i) * 136 + jp * 4) = pk;
            }
            if (tid < 64) Mskf[tid] = (mask[b * S + j0 + tid] == 0) ? -1e9f : 0.f;
        }
        __syncthreads();

        // ---- S^T = K @ Q^T (log2-scaled); K-frags read once ----
        f32x4 st[2][4] = {};
        #pragma unroll
        for (int ks = 0; ks < 2; ++ks) {
            #pragma unroll
            for (int jt = 0; jt < 4; ++jt) {
                union { uint u[4]; bf16x8 v; } kf;
                const uint* bp = (const uint*)((const char*)&Ks[0][0]
                                 + (size_t)(jt * 16 + n) * 132 + ks * 64 + kg * 16);
                kf.u[0] = bp[0]; kf.u[1] = bp[1]; kf.u[2] = bp[2]; kf.u[3] = bp[3];
                st[0][jt] = __builtin_amdgcn_mfma_f32_16x16x32_bf16(kf.v, qf[0][ks], st[0][jt], 0, 0, 0);
                st[1][jt] = __builtin_amdgcn_mfma_f32_16x16x32_bf16(kf.v, qf[1][ks], st[1][jt], 0, 0, 0);
            }
        }

        // ---- online softmax per group (native v_exp_f32, truncation-pack) --
        bf16x4v pf[2][4];
        #pragma unroll
        for (int u = 0; u < 2; ++u) {
            float mx = m[u];
            #pragma unroll
            for (int jt = 0; jt < 4; ++jt) {
                f32x4 mb = *(const f32x4*)&Mskf[jt * 16 + kg * 4];
                #pragma unroll
                for (int r = 0; r < 4; ++r) {
                    st[u][jt][r] += mb[r];
                    mx = fmaxf(mx, st[u][jt][r]);
                }
            }
            mx = fmaxf(mx, __shfl_xor(mx, 16, 64));
            mx = fmaxf(mx, __shfl_xor(mx, 32, 64));
            float alpha = EXP2F(m[u] - mx);
            m[u] = mx;
            float ls = 0.f;
            #pragma unroll
            for (int jt = 0; jt < 4; ++jt) {
                union { unsigned short s[4]; bf16x4v v; } pk;
                #pragma unroll
                for (int r = 0; r < 4; ++r) {
                    union { float f; unsigned int u2; } p;
                    p.f = EXP2F(st[u][jt][r] - mx);
                    p.u2 &= 0xffff0000u;          // truncate to bf16
                    ls += p.f;                    // sum the truncated value
                    pk.s[r] = (unsigned short)(p.u2 >> 16);
                }
                pf[u][jt] = pk.v;
            }
            ls += __shfl_xor(ls, 16, 64);
            ls += __shfl_xor(ls, 32, 64);
            l[u] = l[u] * alpha + ls;
            #pragma unroll
            for (int dt = 0; dt < 4; ++dt)
                #pragma unroll
                for (int r = 0; r < 4; ++r) acc[u][dt][r] *= alpha;
        }

        // ---- O^T += V^T @ P^T; V-frags read once ----
        #pragma unroll
        for (int jt = 0; jt < 4; ++jt) {
            #pragma unroll
            for (int dt = 0; dt < 4; ++dt) {
                union { uint u[2]; bf16x4v v; } vf;
                const uint* vpp = (const uint*)((const char*)&Vt[0][0]
                                  + (size_t)(dt * 16 + n) * 136 + jt * 32 + kg * 8);
                vf.u[0] = vpp[0]; vf.u[1] = vpp[1];
                acc[0][dt] = __builtin_amdgcn_mfma_f32_16x16x16bf16_1k(vf.v, pf[0][jt], acc[0][dt], 0, 0, 0);
                acc[1][dt] = __builtin_amdgcn_mfma_f32_16x16x16bf16_1k(vf.v, pf[1][jt], acc[1][dt], 0, 0, 0);
            }
        }
    }

    // ---- epilogue ----
    #pragma unroll
    for (int u = 0; u < 2; ++u) {
        float inv = (l[u] > 0.f) ? (1.f / l[u]) : 0.f;
        bf16* op = outp + ((size_t)(b * S + q0 + wid * 32 + u * 16 + n)) * Do + h * 64;
        #pragma unroll
        for (int dt = 0; dt < 4; ++dt) {
            union { unsigned short s[4]; uint2 u2; } w;
            #pragma unroll
            for (int r = 0; r < 4; ++r) w.s[r] = bf16bits(acc[u][dt][r] * inv);
            *(uint2*)(op + dt * 16 + kg * 4) = w.u2;
        }
    }
}
#else
// Fallback (round-5 structure); handles 128 q-rows as two sequential halves.
__global__ __launch_bounds__(256) void attn_mfma(const bf16* __restrict__ qkv,
                                                 const int* __restrict__ mask,
                                                 bf16* __restrict__ outp,
                                                 int B, int S, int LD) {
    const int h = blockIdx.y, b = blockIdx.z;
    const int Do = 1024;
    const int tid = threadIdx.x, lane = tid & 63, wid = tid >> 6;
    const int n = lane & 15, kg = lane >> 4;

    __shared__ bf16 Ks[64][66];
    __shared__ bf16 Vt[64][66];
    __shared__ bf16 Plds[4][16][66];
    __shared__ int  Msk[64];

    for (int half = 0; half < 2; ++half) {
        const int q0 = blockIdx.x * 128 + half * 64;
        __syncthreads();

        bf16x8 qf[2];
        {
            const bf16* qp = qkv + ((size_t)(b * S + q0 + wid * 16 + n)) * LD + h * 64 + kg * 8;
            union { uint4 u; bf16x8 v; } c0, c1;
            c0.u = *(const uint4*)qp;
            c1.u = *(const uint4*)(qp + 32);
            qf[0] = c0.v; qf[1] = c1.v;
        }

        f32x4 acc_o[4] = {};
        float m_r[4] = {-1e30f, -1e30f, -1e30f, -1e30f};
        float l_r[4] = {0.f, 0.f, 0.f, 0.f};

        const int sr = tid >> 2;
        const int sc = (tid & 3) * 16;
        const bf16* kbase = qkv + (size_t)(b * S) * LD + 1024 + h * 64;
        const bf16* vbase = qkv + (size_t)(b * S) * LD + 2048 + h * 64;

        for (int j0 = 0; j0 < S; j0 += 64) {
            __syncthreads();
            {
                const bf16* kp = kbase + (size_t)(j0 + sr) * LD + sc;
                uint4 ka = *(const uint4*)kp;
                uint4 kbv = *(const uint4*)(kp + 8);
                uint* kd = (uint*)((char*)&Ks[0][0] + sr * 132 + sc * 2);
                kd[0] = ka.x; kd[1] = ka.y; kd[2] = ka.z; kd[3] = ka.w;
                kd[4] = kbv.x; kd[5] = kbv.y; kd[6] = kbv.z; kd[7] = kbv.w;

                const bf16* vp = vbase + (size_t)(j0 + sr) * LD + sc;
                union { uint4 u[2]; unsigned short s[16]; } vv;
                vv.u[0] = *(const uint4*)vp;
                vv.u[1] = *(const uint4*)(vp + 8);
                #pragma unroll
                for (int i = 0; i < 16; ++i)
                    *((unsigned short*)((char*)&Vt[0][0] + (size_t)(sc + i) * 132 + sr * 2)) = vv.s[i];

                if (tid < 64) Msk[tid] = mask[b * S + j0 + tid];
            }
            __syncthreads();

            f32x4 st[4] = {};
            #pragma unroll
            for (int ks = 0; ks < 2; ++ks) {
                #pragma unroll
                for (int jt = 0; jt < 4; ++jt) {
                    union { uint u[4]; bf16x8 v; } bf;
                    const uint* bp = (const uint*)((const char*)&Ks[0][0]
                                     + (size_t)(jt * 16 + n) * 132 + ks * 64 + kg * 16);
                    bf.u[0] = bp[0]; bf.u[1] = bp[1]; bf.u[2] = bp[2]; bf.u[3] = bp[3];
                    st[jt] = __builtin_amdgcn_mfma_f32_16x16x32_bf16(qf[ks], bf.v, st[jt], 0, 0, 0);
                }
            }

            int mk[4];
            #pragma unroll
            for (int jt = 0; jt < 4; ++jt) mk[jt] = Msk[jt * 16 + n];

            #pragma unroll
            for (int r = 0; r < 4; ++r) {
                float mx = -1e30f;
                #pragma unroll
                for (int jt = 0; jt < 4; ++jt) {
                    float s = st[jt][r] * 0.125f;
                    if (mk[jt] == 0) s = -1e9f;
                    st[jt][r] = s;
                    mx = fmaxf(mx, s);
                }
                #pragma unroll
                for (int o = 1; o < 16; o <<= 1) mx = fmaxf(mx, __shfl_xor(mx, o, 64));
                float newm = fmaxf(m_r[r], mx);
                float alpha = __expf(m_r[r] - newm);
                m_r[r] = newm;
                float ls = 0.f;
                #pragma unroll
                for (int jt = 0; jt < 4; ++jt) {
                    float p = __expf(st[jt][r] - newm);
                    ls += p;
                    Plds[wid][kg * 4 + r][jt * 16 + n] = __float2bfloat16(p);
                }
                #pragma unroll
                for (int o = 1; o < 16; o <<= 1) ls += __shfl_xor(ls, o, 64);
                l_r[r] = l_r[r] * alpha + ls;
                #pragma unroll
                for (int dt = 0; dt < 4; ++dt) acc_o[dt][r] *= alpha;
            }

            __asm__ volatile("s_waitcnt lgkmcnt(0)" ::: "memory");

            #pragma unroll
            for (int ks = 0; ks < 2; ++ks) {
                union { uint u[4]; bf16x8 v; } af;
                const uint* ap = (const uint*)((const char*)&Plds[wid][0][0]
                                 + (size_t)n * 132 + ks * 64 + kg * 16);
                af.u[0] = ap[0]; af.u[1] = ap[1]; af.u[2] = ap[2]; af.u[3] = ap[3];
                #pragma unroll
                for (int dt = 0; dt < 4; ++dt) {
                    union { uint u[4]; bf16x8 v; } bf;
                    const uint* bp = (const uint*)((const char*)&Vt[0][0]
                                     + (size_t)(dt * 16 + n) * 132 + ks * 64 + kg * 16);
                    bf.u[0] = bp[0]; bf.u[1] = bp[1]; bf.u[2] = bp[2]; bf.u[3] = bp[3];
                    acc_o[dt] = __builtin_amdgcn_mfma_f32_16x16x32_bf16(af.v, bf.v, acc_o[dt], 0, 0, 0);
                }
            }
        }

        #pragma unroll
        for (int r = 0; r < 4; ++r) {
            float inv = (l_r[r] > 0.f) ? (1.f / l_r[r]) : 0.f;
            bf16* op = outp + ((size_t)(b * S + q0 + wid * 16 + kg * 4 + r)) * Do + h * 64 + n;
            #pragma unroll
            for (int dt = 0; dt < 4; ++dt)
                op[dt * 16] = __float2bfloat16(acc_o[dt][r] * inv);
        }
    }
}
#endif

extern "C" void kernel_launch(void* const* d_in, const int* in_sizes, int n_in,
                              void* d_out, int out_size, void* d_ws, size_t ws_size,
                              hipStream_t stream) {
    const int B = 2, S = 2048, D = 1024, H = 16, F = 4096;
    const int M = B * S;  // 4096

    const float* x   = (const float*)d_in[0];
    const int*   mask= (const int*)  d_in[1];
    const float* wq  = (const float*)d_in[2];
    const float* bq  = (const float*)d_in[3];
    const float* wk  = (const float*)d_in[4];
    const float* bk  = (const float*)d_in[5];
    const float* wv  = (const float*)d_in[6];
    const float* bv  = (const float*)d_in[7];
    const float* wo  = (const float*)d_in[8];
    const float* bo  = (const float*)d_in[9];
    const float* g1  = (const float*)d_in[10];
    const float* be1 = (const float*)d_in[11];
    const float* g2  = (const float*)d_in[12];
    const float* be2 = (const float*)d_in[13];
    const float* w1  = (const float*)d_in[14];
    const float* bf1 = (const float*)d_in[15];
    const float* w2  = (const float*)d_in[16];
    const float* bf2 = (const float*)d_in[17];
    float* out = (float*)d_out;

    char* ws = (char*)d_ws;
    const size_t MB = 1024 * 1024;
    bf16* wqkvT = (bf16*)(ws + 0 * MB);            // [3072,1024]
    bf16* woT   = (bf16*)(ws + 6 * MB);
    bf16* w1T   = (bf16*)(ws + 8 * MB);
    bf16* w2T   = (bf16*)(ws + 16 * MB);
    bf16* xn    = (bf16*)(ws + 24 * MB);
    bf16* qkv   = (bf16*)(ws + 32 * MB);           // [4096,3072]
    bf16* att   = xn;                              // reuse
    // x2 (fp32 residual carrier) lives in d_out.

    const bool fullM = (ws_size >= 64 * MB);

    transpose_all<<<12288, 256, 0, stream>>>(wq, wk, wv, wo, w1, w2,
                                             wqkvT, woT, w1T, w2T);

    ln_kernel<float><<<M, 256, 0, stream>>>(x, g1, be1, xn, D);

    gemm_mfma<128, bf16, float, false, false, true><<<dim3(3072 / 128, M / 128), 256, 0, stream>>>(
        xn, wqkvT, bq, bk, bv, (const float*)nullptr, qkv, M, 3072, D);

    attn_mfma<<<dim3(S / 128, H, B), 256, 0, stream>>>(qkv, mask, att, B, S, 3072);

    gemm_mfma<64, float, float, false, true, false><<<dim3(D / 128, M / 64), 256, 0, stream>>>(
        att, woT, bo, nullptr, nullptr, x, out, M, D, D);

    if (fullM) {
        bf16* hid = (bf16*)(ws + 24 * MB);   // [4096,4096] at [24,56)
        bf16* xn2 = (bf16*)(ws + 56 * MB);   // [4096,1024] at [56,64)
        ln_kernel<float><<<M, 256, 0, stream>>>(out, g2, be2, xn2, D);
        gemm_mfma<128, bf16, float, true, false, false><<<dim3(F / 128, M / 128), 256, 0, stream>>>(
            xn2, w1T, bf1, nullptr, nullptr, (const float*)nullptr, hid, M, F, D);
        gemm_mfma<64, float, float, false, true, false><<<dim3(D / 128, M / 64), 256, 0, stream>>>(
            hid, w2T, bf2, nullptr, nullptr, out, out, M, D, F);
    } else {
        bf16* xn2 = (bf16*)(ws + 32 * MB);   // q-section reuse
        bf16* hid = (bf16*)(ws + 40 * MB);   // k+v sections, [2048,4096]
        const int CH = 2048;
        ln_kernel<float><<<M, 256, 0, stream>>>(out, g2, be2, xn2, D);
        for (int c = 0; c < M / CH; ++c) {
            const size_t roff = (size_t)c * CH;
            gemm_mfma<128, bf16, float, true, false, false><<<dim3(F / 128, CH / 128), 256, 0, stream>>>(
                xn2 + roff * D, w1T, bf1, nullptr, nullptr, (const float*)nullptr, hid, CH, F, D);
            gemm_mfma<64, float, float, false, true, false><<<dim3(D / 128, CH / 64), 256, 0, stream>>>(
                hid, w2T, bf2, nullptr, nullptr, out + roff * D, out + roff * D, CH, D, F);
        }
    }
}